// Round 16
// baseline (1989.674 us; speedup 1.0000x reference)
//
#include <hip/hip_runtime.h>
#include <cstdint>
#include <cstddef>

using u16 = unsigned short;
using bf16x8 = __attribute__((ext_vector_type(8))) short;
using f32x4  = __attribute__((ext_vector_type(4))) float;

// ---------- helpers ----------
__device__ __forceinline__ u16 f2bf(float f) {
    union { float f; unsigned u; } v; v.f = f;
    unsigned r = v.u + 0x7fffu + ((v.u >> 16) & 1u);   // RNE
    return (u16)(r >> 16);
}

__device__ __forceinline__ float bf2f(u16 b) {
    union { unsigned u; float f; } v; v.u = (unsigned)b << 16;
    return v.f;
}

__device__ __forceinline__ unsigned cvtpk(float lo, float hi) {
    unsigned r;
    asm("v_cvt_pk_bf16_f32 %0, %1, %2" : "=v"(r) : "v"(lo), "v"(hi));
    return r;
}

// raw v_exp_f32: D = 2^S0 (native TRANS op)
__device__ __forceinline__ float fexp2(float x) {
    float r;
    asm("v_exp_f32 %0, %1" : "=v"(r) : "v"(x));
    return r;
}

// tanh-form GELU via native exp2: x * sigmoid(2t), 2t*log2e = x*(a2+b2*x^2)
__device__ __forceinline__ float gelu_f(float x) {
    const float t2 = fminf(x * fmaf(0.10294825f, x * x, 2.3022082f), 80.f);
    const float e  = fexp2(t2);
    return x * e * __frcp_rn(e + 1.0f);
}

__device__ __forceinline__ void gld_lds16(const void* g, void* l) {
    __builtin_amdgcn_global_load_lds(
        (__attribute__((address_space(1))) void*)g,
        (__attribute__((address_space(3))) void*)l, 16, 0, 0);
}

__device__ __forceinline__ f32x4 mfma16(bf16x8 a, bf16x8 b, f32x4 c) {
    return __builtin_amdgcn_mfma_f32_16x16x32_bf16(a, b, c, 0, 0, 0);
}

// ---------- merged prepass: 6 weight transposes + x cast (1 launch) ----------
// blocks [0,12288): weight tcast; [12288,16384): x fp32->bf16 cast
__global__ __launch_bounds__(256)
void prepass_kernel(const float* __restrict__ Wq, const float* __restrict__ Wk,
                    const float* __restrict__ Wv, const float* __restrict__ Wo,
                    const float* __restrict__ W1, const float* __restrict__ W2,
                    const float* __restrict__ x,
                    u16* __restrict__ wqkvt, u16* __restrict__ wot,
                    u16* __restrict__ w1t, u16* __restrict__ w2t,
                    u16* __restrict__ xb)
{
    const int g = blockIdx.x;
    if (g >= 12288) {
        const int i = (g - 12288) * 256 + threadIdx.x;   // i < 1048576
        const float4* p = (const float4*)x;
        float4 a = p[i * 2], b = p[i * 2 + 1];
        ushort4 r0 = make_ushort4(f2bf(a.x), f2bf(a.y), f2bf(a.z), f2bf(a.w));
        ushort4 r1 = make_ushort4(f2bf(b.x), f2bf(b.y), f2bf(b.z), f2bf(b.w));
        ((ushort4*)xb)[i * 2]     = r0;
        ((ushort4*)xb)[i * 2 + 1] = r1;
        return;
    }
    const float* src; u16* dst; int K, N, ti; float scale = 1.0f;
    if (g < 1024)      { src = Wq; dst = wqkvt;               K = 1024; N = 1024; ti = g;        scale = 0.18033688011112042f; }
    else if (g < 2048) { src = Wk; dst = wqkvt + 1048576;     K = 1024; N = 1024; ti = g - 1024; }
    else if (g < 3072) { src = Wv; dst = wqkvt + 2097152;     K = 1024; N = 1024; ti = g - 2048; }
    else if (g < 4096) { src = Wo; dst = wot;                 K = 1024; N = 1024; ti = g - 3072; }
    else if (g < 8192) { src = W1; dst = w1t;                 K = 1024; N = 4096; ti = g - 4096; }
    else               { src = W2; dst = w2t;                 K = 4096; N = 1024; ti = g - 8192; }
    const int nt = N >> 5;
    const int bx = ti % nt, by = ti / nt;
    const int k0 = by * 32, n0 = bx * 32;

    __shared__ float tile[32][33];
    const int tx = threadIdx.x & 31, ty = threadIdx.x >> 5;
    #pragma unroll
    for (int r = 0; r < 4; ++r) {
        int k = ty * 4 + r;
        tile[k][tx] = src[(size_t)(k0 + k) * N + n0 + tx];
    }
    __syncthreads();
    const int kx = (threadIdx.x & 15) * 2;
    const int ny = threadIdx.x >> 4;
    #pragma unroll
    for (int r = 0; r < 2; ++r) {
        const int n = ny * 2 + r;
        ushort2 o = make_ushort2(f2bf(tile[kx][n] * scale),
                                 f2bf(tile[kx + 1][n] * scale));
        *(ushort2*)&dst[(size_t)(n0 + n) * K + k0 + kx] = o;
    }
}

// ---------- bias concat for fused QKV (q scaled by 0.125*log2e) ----------
__global__ __launch_bounds__(256)
void bias_concat_kernel(const float* __restrict__ bq, const float* __restrict__ bk,
                        const float* __restrict__ bv, float* __restrict__ out) {
    int i = blockIdx.x * 256 + threadIdx.x;
    if (i >= 3072) return;
    float v;
    if (i < 1024)      v = bq[i] * 0.18033688011112042f;   // 0.125 * log2(e)
    else if (i < 2048) v = bk[i - 1024];
    else               v = bv[i - 2048];
    out[i] = v;
}

// ---------- BK=32 single-phase counted-vmcnt GEMM, multi-block/CU ----------
// BN=256, 512 threads (8 waves, 2M x 4N), 2 LDS buffers of (BM*64 + 16KB).
// BM=128: 48KB LDS -> 3 blocks/CU; BM=256: 64KB -> 2 blocks/CU. Cross-block
// wave overlap covers barrier/vmcnt stalls (m97/m103 mechanism) — single-
// block phase-schedule variants all plateaued at MfmaUtil ~33%.
// Per K-tile: { stage(t+1 -> other buf) | vmcnt(NLD) | barrier |
//               ds_read 4 B + MR A frags | MR*4 MFMA | barrier }.
// vmcnt(NLD) retires exactly tile t's own loads (t+1's NLD remain in flight);
// post-MFMA barrier guarantees all readers of a buffer finished (lgkm-waited
// by their MFMAs) before any wave stages the next tile into it.
// Line-XOR LDS layout (conflict-free); n-major + bijective XCD block map.
// EPI: 0 = bf16, 2 = GELU->bf16
template <int BM, int EPI>
__global__ __launch_bounds__(512, (BM == 128 ? 6 : 4))
void gemm_bk32_kernel(const u16* __restrict__ A, const u16* __restrict__ Bt,
                      const float* __restrict__ bias, void* __restrict__ Cout,
                      int M, int N, int K)
{
    constexpr int AH  = BM * 64;      // A region bytes / buffer
    constexpr int BH  = 16384;        // B region bytes / buffer
    constexpr int BUF = AH + BH;
    constexpr int LPA = BM / 128;     // A loads/thread/stage (1 or 2)
    constexpr int NLD = LPA + 2;      // loads/thread/stage total (3 or 4)
    constexpr int MR  = BM / 32;      // A frags per wave

    extern __shared__ char smem[];

    const int tid  = threadIdx.x;
    const int wid  = tid >> 6, lane = tid & 63;
    const int l15  = lane & 15, l4 = lane >> 4;
    const int wm   = wid >> 2, wn = wid & 3;

    const int nwg = gridDim.x;
    const int qx = nwg >> 3, rx = nwg & 7;
    const int orig = blockIdx.x;
    const int xcd = orig & 7, jx = orig >> 3;
    const int wgid = (xcd < rx ? xcd * (qx + 1) : rx * (qx + 1) + (xcd - rx) * qx) + jx;
    const int NTn = N / 256;
    const int m0 = (wgid / NTn) * BM;     // n-major: neighbors share A-panel
    const int n0 = (wgid % NTn) * 256;

    const int q0 = tid >> 3, g0 = tid & 7;
    const int u0 = g0 ^ (q0 & 7);
    const int r0 = (q0 << 1) | (u0 >> 2), c80 = u0 & 3;
    const int q1 = q0 + 64;
    const int u1 = g0 ^ (q1 & 7);
    const int r1 = (q1 << 1) | (u1 >> 2), c81 = u1 & 3;
    const u16* aP0 = A  + (size_t)(m0 + r0) * K + c80 * 8;
    const u16* aP1 = A  + (size_t)(m0 + r1) * K + c81 * 8;   // BM=256 only
    const u16* bP0 = Bt + (size_t)(n0 + r0) * K + c80 * 8;
    const u16* bP1 = Bt + (size_t)(n0 + r1) * K + c81 * 8;
    const int NT = K >> 5;

    auto stage = [&](int tt, int sb) {
        const int kte = tt << 5;
        char* da = smem + sb * BUF + tid * 16;
        gld_lds16(aP0 + kte, da);
        if constexpr (LPA == 2) gld_lds16(aP1 + kte, da + 8192);
        char* db = smem + sb * BUF + AH + tid * 16;
        gld_lds16(bP0 + kte, db);
        gld_lds16(bP1 + kte, db + 8192);
    };

    auto frag_off = [&](int row) -> int {
        const int q = row >> 1;
        const int u = ((row & 1) << 2) | l4;
        const int g = u ^ (q & 7);
        return q * 128 + g * 16;
    };

    f32x4 acc[MR][4];
    #pragma unroll
    for (int i = 0; i < MR; ++i)
        #pragma unroll
        for (int jj = 0; jj < 4; ++jj) acc[i][jj] = f32x4{0.f, 0.f, 0.f, 0.f};

    stage(0, 0);

    for (int t = 0; t < NT; ++t) {
        const int tn = (t + 1 < NT) ? t + 1 : t;     // tail dup (never read)
        stage(tn, (t + 1) & 1);
        if constexpr (NLD == 4) asm volatile("s_waitcnt vmcnt(4)" ::: "memory");
        else                    asm volatile("s_waitcnt vmcnt(3)" ::: "memory");
        __builtin_amdgcn_s_barrier();
        asm volatile("" ::: "memory");

        const char* buf = smem + (t & 1) * BUF;
        bf16x8 bfr[4], af[MR];
        #pragma unroll
        for (int fc = 0; fc < 4; ++fc)
            bfr[fc] = *(const bf16x8*)(buf + AH + frag_off(wn * 64 + fc * 16 + l15));
        #pragma unroll
        for (int i = 0; i < MR; ++i)
            af[i] = *(const bf16x8*)(buf + frag_off(wm * (BM / 2) + i * 16 + l15));

        __builtin_amdgcn_s_setprio(1);
        #pragma unroll
        for (int i = 0; i < MR; ++i)
            #pragma unroll
            for (int fc = 0; fc < 4; ++fc)
                acc[i][fc] = mfma16(af[i], bfr[fc], acc[i][fc]);
        __builtin_amdgcn_s_setprio(0);
        asm volatile("" ::: "memory");
        __builtin_amdgcn_s_barrier();    // readers-done fence for buffer reuse
        asm volatile("" ::: "memory");
    }

    float bv[4];
    #pragma unroll
    for (int fc = 0; fc < 4; ++fc) bv[fc] = bias[n0 + wn * 64 + fc * 16 + l15];
    #pragma unroll
    for (int fr = 0; fr < MR; ++fr) {
        const int rowg = m0 + wm * (BM / 2) + fr * 16 + l4 * 4;
        #pragma unroll
        for (int fc = 0; fc < 4; ++fc) {
            const int colg = n0 + wn * 64 + fc * 16 + l15;
            #pragma unroll
            for (int r = 0; r < 4; ++r) {
                const float v = acc[fr][fc][r] + bv[fc];
                const size_t off = (size_t)(rowg + r) * N + colg;
                if (EPI == 0) ((u16*)Cout)[off] = f2bf(v);
                else          ((u16*)Cout)[off] = f2bf(gelu_f(v));
            }
        }
    }
}

// ---------- V transpose: qkv[b*2048+s][2048 + h*64+d] -> Vt[bh][d][s] ----------
__global__ __launch_bounds__(256)
void vtrans_kernel(const u16* __restrict__ QKV, u16* __restrict__ Vt) {
    __shared__ u16 tile[64][68];
    const int t  = threadIdx.x;
    const int st = blockIdx.x, bh = blockIdx.y;
    const int b  = bh >> 4, h = bh & 15;
    #pragma unroll
    for (int i = 0; i < 2; ++i) {
        int sl = i * 32 + (t >> 3);
        const u16* gp = QKV + ((size_t)b * 2048 + st * 64 + sl) * 3072 + 2048 + h * 64 + (t & 7) * 8;
        ushort4 a = *(const ushort4*)gp;
        ushort4 c = *(const ushort4*)(gp + 4);
        u16* lp = &tile[sl][(t & 7) * 8];
        *(ushort4*)lp       = a;
        *(ushort4*)(lp + 4) = c;
    }
    __syncthreads();
    #pragma unroll
    for (int i = 0; i < 2; ++i) {
        int d  = i * 32 + (t >> 3);
        int s8 = (t & 7) * 8;
        ushort4 o0, o1;
        o0.x = tile[s8 + 0][d]; o0.y = tile[s8 + 1][d]; o0.z = tile[s8 + 2][d]; o0.w = tile[s8 + 3][d];
        o1.x = tile[s8 + 4][d]; o1.y = tile[s8 + 5][d]; o1.z = tile[s8 + 6][d]; o1.w = tile[s8 + 7][d];
        u16* op = Vt + ((size_t)bh * 64 + d) * 2048 + st * 64 + s8;
        *(ushort4*)op       = o0;
        *(ushort4*)(op + 4) = o1;
    }
}

// ---------- flash attention: QBLK=256, 8 waves; XCD-aligned grid ----------
__global__ __launch_bounds__(512)
void attn_kernel(const u16* __restrict__ QKV, const u16* __restrict__ Vt,
                 u16* __restrict__ ctx)
{
    __shared__ u16 smem[24576];

    const int tid = threadIdx.x;
    const int wid = tid >> 6, lane = tid & 63;
    const int l15 = lane & 15, l4 = lane >> 4;
    const int sw  = l15 & 7;
    const int lr  = lane >> 3;
    const int gsrc = ((lane & 7) ^ lr) * 8;
    const int g   = blockIdx.x;
    const int bh  = (g & 7) | ((g >> 6) << 3);
    const int qt  = (g >> 3) & 7;
    const int b = bh >> 4, h = bh & 15;
    const size_t qrow0 = (size_t)b * 2048 + (size_t)qt * 256;

    u16* const K0 = smem + 16384;
    u16* const V0 = smem + 20480;
    u16* const K1 = smem;
    u16* const V1 = smem + 4096;

    const u16* Qbase = QKV + h * 64;
    const u16* Kbase = QKV + (size_t)b * 2048 * 3072 + 1024 + h * 64;
    const u16* Vbase = Vt + (size_t)bh * 64 * 2048;

    #pragma unroll
    for (int c = 0; c < 4; ++c) {
        const int chunk = wid * 4 + c;
        const int row = chunk * 8 + lr;
        gld_lds16(Qbase + (qrow0 + row) * 3072 + gsrc,
                  (char*)smem + chunk * 1024);
    }

    auto stage_kv = [&](int kt, u16* kb, u16* vb) {
        const int rho = wid * 8 + lr;
        const int krow = (rho & 32) + ((rho & 16) >> 2) + ((rho & 12) << 1) + (rho & 3);
        gld_lds16(Kbase + (size_t)(kt + krow) * 3072 + gsrc,
                  (char*)kb + wid * 1024);
        gld_lds16(Vbase + (size_t)rho * 2048 + kt + gsrc,
                  (char*)vb + wid * 1024);
    };

    stage_kv(0, K0, V0);
    __syncthreads();

    bf16x8 qf[2][2];
    #pragma unroll
    for (int mi = 0; mi < 2; ++mi)
        #pragma unroll
        for (int kk = 0; kk < 2; ++kk)
            qf[mi][kk] = *(const bf16x8*)
                &smem[(size_t)(wid * 32 + mi * 16 + l15) * 64 + (((kk * 4 + l4) ^ sw) * 8)];
    __syncthreads();

    f32x4 accO[2][4] = {};
    f32x4 accL[2] = {};
    const short one_bf = (short)0x3F80;
    const bf16x8 ones = {one_bf, one_bf, one_bf, one_bf,
                         one_bf, one_bf, one_bf, one_bf};

    union U4 { unsigned u[4]; bf16x8 v; };

    auto compute_tile = [&](const u16* kb, const u16* vb) {
        f32x4 st[2][4];
        #pragma unroll
        for (int mi = 0; mi < 2; ++mi)
            #pragma unroll
            for (int ni = 0; ni < 4; ++ni) st[mi][ni] = f32x4{0.f, 0.f, 0.f, 0.f};
        __builtin_amdgcn_s_setprio(1);
        #pragma unroll
        for (int ni = 0; ni < 4; ++ni) {
            bf16x8 kf0 = *(const bf16x8*)&kb[(ni * 16 + l15) * 64 + ((l4 ^ sw) * 8)];
            bf16x8 kf1 = *(const bf16x8*)&kb[(ni * 16 + l15) * 64 + (((4 + l4) ^ sw) * 8)];
            #pragma unroll
            for (int mi = 0; mi < 2; ++mi) {
                st[mi][ni] = mfma16(kf0, qf[mi][0], st[mi][ni]);
                st[mi][ni] = mfma16(kf1, qf[mi][1], st[mi][ni]);
            }
        }
        __builtin_amdgcn_s_setprio(0);

        U4 pb[2][2];
        #pragma unroll
        for (int mi = 0; mi < 2; ++mi) {
            float p[4][4];
            #pragma unroll
            for (int ni = 0; ni < 4; ++ni)
                #pragma unroll
                for (int r = 0; r < 4; ++r)
                    p[ni][r] = fexp2(st[mi][ni][r]);
            #pragma unroll
            for (int ni = 0; ni < 4; ++ni) {
                pb[mi][ni >> 1].u[(ni & 1) * 2 + 0] = cvtpk(p[ni][0], p[ni][1]);
                pb[mi][ni >> 1].u[(ni & 1) * 2 + 1] = cvtpk(p[ni][2], p[ni][3]);
            }
        }

        __builtin_amdgcn_s_setprio(1);
        #pragma unroll
        for (int mi = 0; mi < 2; ++mi) {
            accL[mi] = mfma16(ones, pb[mi][0].v, accL[mi]);
            accL[mi] = mfma16(ones, pb[mi][1].v, accL[mi]);
        }
        #pragma unroll
        for (int di = 0; di < 4; ++di) {
            bf16x8 vf0 = *(const bf16x8*)&vb[(di * 16 + l15) * 64 + ((l4 ^ sw) * 8)];
            bf16x8 vf1 = *(const bf16x8*)&vb[(di * 16 + l15) * 64 + (((4 + l4) ^ sw) * 8)];
            #pragma unroll
            for (int mi = 0; mi < 2; ++mi) {
                accO[mi][di] = mfma16(vf0, pb[mi][0].v, accO[mi][di]);
                accO[mi][di] = mfma16(vf1, pb[mi][1].v, accO[mi][di]);
            }
        }
        __builtin_amdgcn_s_setprio(0);
    };

    for (int it = 0; it < 32; it += 2) {
        if (it + 1 < 32) stage_kv((it + 1) * 64, K1, V1);
        compute_tile(K0, V0);
        __syncthreads();
        if (it + 2 < 32) stage_kv((it + 2) * 64, K0, V0);
        compute_tile(K1, V1);
        __syncthreads();
    }

    #pragma unroll
    for (int mi = 0; mi < 2; ++mi) {
        const float inv = 1.0f / accL[mi][0];
        const size_t q = qrow0 + wid * 32 + mi * 16 + l15;
        #pragma unroll
        for (int di = 0; di < 4; ++di) {
            uint2 w;
            w.x = cvtpk(accO[mi][di][0] * inv, accO[mi][di][1] * inv);
            w.y = cvtpk(accO[mi][di][2] * inv, accO[mi][di][3] * inv);
            *(uint2*)&ctx[q * 1024 + h * 64 + di * 16 + l4 * 4] = w;
        }
    }
}

// ---------- fused add + layernorm; X,Y bf16; outputs f32 and/or bf16 ----------
__global__ __launch_bounds__(256)
void add_ln_kernel(const u16* __restrict__ X, const u16* __restrict__ Y,
                   const float* __restrict__ gamma, const float* __restrict__ beta,
                   float* __restrict__ outf, u16* __restrict__ outb)
{
    const int row = blockIdx.x;
    const int t = threadIdx.x;
    const ushort4 xb = ((const ushort4*)(X + (size_t)row * 1024))[t];
    const ushort4 yb = ((const ushort4*)(Y + (size_t)row * 1024))[t];
    const float v0 = bf2f(xb.x) + bf2f(yb.x);
    const float v1 = bf2f(xb.y) + bf2f(yb.y);
    const float v2 = bf2f(xb.z) + bf2f(yb.z);
    const float v3 = bf2f(xb.w) + bf2f(yb.w);
    float s  = v0 + v1 + v2 + v3;
    float ss = v0 * v0 + v1 * v1 + v2 * v2 + v3 * v3;
    #pragma unroll
    for (int m = 1; m < 64; m <<= 1) {
        s  += __shfl_xor(s, m, 64);
        ss += __shfl_xor(ss, m, 64);
    }
    __shared__ float red[8];
    const int wid = t >> 6, lane = t & 63;
    if (lane == 0) { red[wid] = s; red[4 + wid] = ss; }
    __syncthreads();
    s  = red[0] + red[1] + red[2] + red[3];
    ss = red[4] + red[5] + red[6] + red[7];
    const float mu  = s * (1.f / 1024.f);
    const float var = ss * (1.f / 1024.f) - mu * mu;
    const float inv = rsqrtf(var + 1e-5f);
    const float4 g  = ((const float4*)gamma)[t];
    const float4 bb = ((const float4*)beta)[t];
    float4 o;
    o.x = (v0 - mu) * inv * g.x + bb.x;
    o.y = (v1 - mu) * inv * g.y + bb.y;
    o.z = (v2 - mu) * inv * g.z + bb.z;
    o.w = (v3 - mu) * inv * g.w + bb.w;
    if (outf != nullptr)
        ((float4*)(outf + (size_t)row * 1024))[t] = o;
    if (outb != nullptr) {
        ushort4 ob = make_ushort4(f2bf(o.x), f2bf(o.y), f2bf(o.z), f2bf(o.w));
        ((ushort4*)(outb + (size_t)row * 1024))[t] = ob;
    }
}

// ---------- launcher ----------
extern "C" void kernel_launch(void* const* d_in, const int* in_sizes, int n_in,
                              void* d_out, int out_size, void* d_ws, size_t ws_size,
                              hipStream_t stream)
{
    (void)in_sizes; (void)n_in; (void)out_size; (void)ws_size;
    const float* x   = (const float*)d_in[0];
    const float* Wq  = (const float*)d_in[1];
    const float* bq  = (const float*)d_in[2];
    const float* Wk  = (const float*)d_in[3];
    const float* bk  = (const float*)d_in[4];
    const float* Wv  = (const float*)d_in[5];
    const float* bv  = (const float*)d_in[6];
    const float* Wo  = (const float*)d_in[7];
    const float* bo  = (const float*)d_in[8];
    const float* g1  = (const float*)d_in[9];
    const float* be1 = (const float*)d_in[10];
    const float* W1  = (const float*)d_in[11];
    const float* b1  = (const float*)d_in[12];
    const float* W2  = (const float*)d_in[13];
    const float* b2  = (const float*)d_in[14];
    const float* g2  = (const float*)d_in[15];
    const float* be2 = (const float*)d_in[16];

    constexpr int M = 8192;
    constexpr int D = 1024;
    constexpr int F = 4096;

    char* ws = (char*)d_ws;
    size_t off = 0;
    auto nxt = [&](size_t bytes) -> char* {
        char* p = ws + off;
        off += (bytes + 255) & ~(size_t)255;
        return p;
    };
    u16*   xb    = (u16*)nxt((size_t)M * D * 2);
    u16*   wqkvt = (u16*)nxt((size_t)3 * D * D * 2);
    u16*   wot   = (u16*)nxt((size_t)D * D * 2);
    u16*   w1t   = (u16*)nxt((size_t)F * D * 2);
    u16*   w2t   = (u16*)nxt((size_t)D * F * 2);
    float* bqkv  = (float*)nxt(3072 * 4);
    u16*   qkv   = (u16*)nxt((size_t)M * 3 * D * 2);
    u16*   Vtb   = (u16*)nxt((size_t)M * D * 2);
    u16*   ctx   = (u16*)nxt((size_t)M * D * 2);
    u16*   attn  = (u16*)nxt((size_t)M * D * 2);
    u16*   hb    = (u16*)nxt((size_t)M * D * 2);
    u16*   t1    = qkv;
    u16*   mlp   = attn;

    // 1. merged prepass (weights tcast + x cast), bias concat
    prepass_kernel<<<dim3(16384), dim3(256), 0, stream>>>(
        Wq, Wk, Wv, Wo, W1, W2, x, wqkvt, wot, w1t, w2t, xb);
    bias_concat_kernel<<<dim3(12), dim3(256), 0, stream>>>(bq, bk, bv, bqkv);

    constexpr size_t LDS128 = 2 * (128 * 64 + 16384);   // 49152 -> 3 blocks/CU
    constexpr size_t LDS256 = 2 * (256 * 64 + 16384);   // 65536 -> 2 blocks/CU

    // 2. fused QKV projection (768 blocks = ONE round at 3/CU)
    gemm_bk32_kernel<128, 0><<<dim3((M / 128) * (3 * D / 256)), dim3(512), LDS128, stream>>>(
        xb, wqkvt, bqkv, qkv, M, 3 * D, D);

    // 3. attention (QBLK=256, XCD-aligned 1-D grid)
    vtrans_kernel<<<dim3(2048 / 64, 64), dim3(256), 0, stream>>>(qkv, Vtb);
    attn_kernel<<<dim3(512), dim3(512), 0, stream>>>(qkv, Vtb, ctx);

    // 4. O projection (bf16 out) + LN1 (bf16 residual chain)
    gemm_bk32_kernel<128, 0><<<dim3((M / 128) * (D / 256)), dim3(512), LDS128, stream>>>(
        ctx, wot, bo, attn, M, D, D);
    add_ln_kernel<<<dim3(M), dim3(256), 0, stream>>>(xb, attn, g1, be1, nullptr, hb);

    // 5. MLP (256^2 MLP1: 512 blocks = one round at 2/CU) + LN2
    gemm_bk32_kernel<256, 2><<<dim3((M / 256) * (F / 256)), dim3(512), LDS256, stream>>>(
        hb, w1t, b1, t1, M, F, D);
    gemm_bk32_kernel<128, 0><<<dim3((M / 128) * (D / 256)), dim3(512), LDS128, stream>>>(
        t1, w2t, b2, mlp, M, D, F);
    add_ln_kernel<<<dim3(M), dim3(256), 0, stream>>>(hb, mlp, g2, be2, (float*)d_out, nullptr);
}

// Round 17
// 364.030 us; speedup vs baseline: 5.4657x; 5.4657x over previous
//
#include <hip/hip_runtime.h>
#include <cstdint>
#include <cstddef>

using u16 = unsigned short;
using bf16x8 = __attribute__((ext_vector_type(8))) short;
using f32x4  = __attribute__((ext_vector_type(4))) float;

// ---------- helpers ----------
__device__ __forceinline__ u16 f2bf(float f) {
    union { float f; unsigned u; } v; v.f = f;
    unsigned r = v.u + 0x7fffu + ((v.u >> 16) & 1u);   // RNE
    return (u16)(r >> 16);
}

__device__ __forceinline__ float bf2f(u16 b) {
    union { unsigned u; float f; } v; v.u = (unsigned)b << 16;
    return v.f;
}

__device__ __forceinline__ unsigned cvtpk(float lo, float hi) {
    unsigned r;
    asm("v_cvt_pk_bf16_f32 %0, %1, %2" : "=v"(r) : "v"(lo), "v"(hi));
    return r;
}

// raw v_exp_f32: D = 2^S0 (native TRANS op)
__device__ __forceinline__ float fexp2(float x) {
    float r;
    asm("v_exp_f32 %0, %1" : "=v"(r) : "v"(x));
    return r;
}

// tanh-form GELU via native exp2
__device__ __forceinline__ float gelu_f(float x) {
    const float t2 = fminf(x * fmaf(0.10294825f, x * x, 2.3022082f), 80.f);
    const float e  = fexp2(t2);
    return x * e * __frcp_rn(e + 1.0f);
}

__device__ __forceinline__ void gld_lds16(const void* g, void* l) {
    __builtin_amdgcn_global_load_lds(
        (__attribute__((address_space(1))) void*)g,
        (__attribute__((address_space(3))) void*)l, 16, 0, 0);
}

__device__ __forceinline__ f32x4 mfma16(bf16x8 a, bf16x8 b, f32x4 c) {
    return __builtin_amdgcn_mfma_f32_16x16x32_bf16(a, b, c, 0, 0, 0);
}

// ---------- merged prepass: 6 weight transposes + x cast (1 launch) ----------
__global__ __launch_bounds__(256)
void prepass_kernel(const float* __restrict__ Wq, const float* __restrict__ Wk,
                    const float* __restrict__ Wv, const float* __restrict__ Wo,
                    const float* __restrict__ W1, const float* __restrict__ W2,
                    const float* __restrict__ x,
                    u16* __restrict__ wqkvt, u16* __restrict__ wot,
                    u16* __restrict__ w1t, u16* __restrict__ w2t,
                    u16* __restrict__ xb)
{
    const int g = blockIdx.x;
    if (g >= 12288) {
        const int i = (g - 12288) * 256 + threadIdx.x;
        const float4* p = (const float4*)x;
        float4 a = p[i * 2], b = p[i * 2 + 1];
        ushort4 r0 = make_ushort4(f2bf(a.x), f2bf(a.y), f2bf(a.z), f2bf(a.w));
        ushort4 r1 = make_ushort4(f2bf(b.x), f2bf(b.y), f2bf(b.z), f2bf(b.w));
        ((ushort4*)xb)[i * 2]     = r0;
        ((ushort4*)xb)[i * 2 + 1] = r1;
        return;
    }
    const float* src; u16* dst; int K, N, ti; float scale = 1.0f;
    if (g < 1024)      { src = Wq; dst = wqkvt;               K = 1024; N = 1024; ti = g;        scale = 0.18033688011112042f; }
    else if (g < 2048) { src = Wk; dst = wqkvt + 1048576;     K = 1024; N = 1024; ti = g - 1024; }
    else if (g < 3072) { src = Wv; dst = wqkvt + 2097152;     K = 1024; N = 1024; ti = g - 2048; }
    else if (g < 4096) { src = Wo; dst = wot;                 K = 1024; N = 1024; ti = g - 3072; }
    else if (g < 8192) { src = W1; dst = w1t;                 K = 1024; N = 4096; ti = g - 4096; }
    else               { src = W2; dst = w2t;                 K = 4096; N = 1024; ti = g - 8192; }
    const int nt = N >> 5;
    const int bx = ti % nt, by = ti / nt;
    const int k0 = by * 32, n0 = bx * 32;

    __shared__ float tile[32][33];
    const int tx = threadIdx.x & 31, ty = threadIdx.x >> 5;
    #pragma unroll
    for (int r = 0; r < 4; ++r) {
        int k = ty * 4 + r;
        tile[k][tx] = src[(size_t)(k0 + k) * N + n0 + tx];
    }
    __syncthreads();
    const int kx = (threadIdx.x & 15) * 2;
    const int ny = threadIdx.x >> 4;
    #pragma unroll
    for (int r = 0; r < 2; ++r) {
        const int n = ny * 2 + r;
        ushort2 o = make_ushort2(f2bf(tile[kx][n] * scale),
                                 f2bf(tile[kx + 1][n] * scale));
        *(ushort2*)&dst[(size_t)(n0 + n) * K + k0 + kx] = o;
    }
}

// ---------- bias concat for fused QKV (q scaled by 0.125*log2e) ----------
__global__ __launch_bounds__(256)
void bias_concat_kernel(const float* __restrict__ bq, const float* __restrict__ bk,
                        const float* __restrict__ bv, float* __restrict__ out) {
    int i = blockIdx.x * 256 + threadIdx.x;
    if (i >= 3072) return;
    float v;
    if (i < 1024)      v = bq[i] * 0.18033688011112042f;
    else if (i < 2048) v = bk[i - 1024];
    else               v = bv[i - 2048];
    out[i] = v;
}

// ---------- BK=32 single-phase GEMM, BM=128, 2 blocks/CU ----------
// 48KB LDS, launch_bounds(512,4): VGPR cap 128 >= ~110 used -> NO spill,
// 4 waves/SIMD = 2 blocks/CU for cross-block stall hiding.
// Per K-tile: { stage(t+1) | vmcnt(3) | bar | ds_read | 16 MFMA | bar }.
template <int EPI>
__global__ __launch_bounds__(512, 4)
void gemm_bk32_kernel(const u16* __restrict__ A, const u16* __restrict__ Bt,
                      const float* __restrict__ bias, void* __restrict__ Cout,
                      int M, int N, int K)
{
    constexpr int AH  = 8192;         // 128*32*2 B
    constexpr int BH  = 16384;        // 256*32*2 B
    constexpr int BUF = AH + BH;

    extern __shared__ char smem[];

    const int tid  = threadIdx.x;
    const int wid  = tid >> 6, lane = tid & 63;
    const int l15  = lane & 15, l4 = lane >> 4;
    const int wm   = wid >> 2, wn = wid & 3;

    const int nwg = gridDim.x;
    const int qx = nwg >> 3, rx = nwg & 7;
    const int orig = blockIdx.x;
    const int xcd = orig & 7, jx = orig >> 3;
    const int wgid = (xcd < rx ? xcd * (qx + 1) : rx * (qx + 1) + (xcd - rx) * qx) + jx;
    const int NTn = N / 256;
    const int m0 = (wgid / NTn) * 128;
    const int n0 = (wgid % NTn) * 256;

    const int q0 = tid >> 3, g0 = tid & 7;
    const int u0 = g0 ^ (q0 & 7);
    const int r0 = (q0 << 1) | (u0 >> 2), c80 = u0 & 3;
    const int q1 = q0 + 64;
    const int u1 = g0 ^ (q1 & 7);
    const int r1 = (q1 << 1) | (u1 >> 2), c81 = u1 & 3;
    const u16* aP0 = A  + (size_t)(m0 + r0) * K + c80 * 8;
    const u16* bP0 = Bt + (size_t)(n0 + r0) * K + c80 * 8;
    const u16* bP1 = Bt + (size_t)(n0 + r1) * K + c81 * 8;
    const int NT = K >> 5;

    auto stage = [&](int tt, int sb) {
        const int kte = tt << 5;
        gld_lds16(aP0 + kte, smem + sb * BUF + tid * 16);
        char* db = smem + sb * BUF + AH + tid * 16;
        gld_lds16(bP0 + kte, db);
        gld_lds16(bP1 + kte, db + 8192);
    };

    auto frag_off = [&](int row) -> int {
        const int q = row >> 1;
        const int u = ((row & 1) << 2) | l4;
        const int g = u ^ (q & 7);
        return q * 128 + g * 16;
    };

    f32x4 acc[4][4];
    #pragma unroll
    for (int i = 0; i < 4; ++i)
        #pragma unroll
        for (int jj = 0; jj < 4; ++jj) acc[i][jj] = f32x4{0.f, 0.f, 0.f, 0.f};

    stage(0, 0);

    for (int t = 0; t < NT; ++t) {
        const int tn = (t + 1 < NT) ? t + 1 : t;
        stage(tn, (t + 1) & 1);
        asm volatile("s_waitcnt vmcnt(3)" ::: "memory");
        __builtin_amdgcn_s_barrier();
        asm volatile("" ::: "memory");

        const char* buf = smem + (t & 1) * BUF;
        bf16x8 bfr[4], af[4];
        #pragma unroll
        for (int fc = 0; fc < 4; ++fc)
            bfr[fc] = *(const bf16x8*)(buf + AH + frag_off(wn * 64 + fc * 16 + l15));
        #pragma unroll
        for (int i = 0; i < 4; ++i)
            af[i] = *(const bf16x8*)(buf + frag_off(wm * 64 + i * 16 + l15));

        __builtin_amdgcn_s_setprio(1);
        #pragma unroll
        for (int i = 0; i < 4; ++i)
            #pragma unroll
            for (int fc = 0; fc < 4; ++fc)
                acc[i][fc] = mfma16(af[i], bfr[fc], acc[i][fc]);
        __builtin_amdgcn_s_setprio(0);
        asm volatile("" ::: "memory");
        __builtin_amdgcn_s_barrier();    // readers-done fence for buffer reuse
        asm volatile("" ::: "memory");
    }

    float bv[4];
    #pragma unroll
    for (int fc = 0; fc < 4; ++fc) bv[fc] = bias[n0 + wn * 64 + fc * 16 + l15];
    #pragma unroll
    for (int fr = 0; fr < 4; ++fr) {
        const int rowg = m0 + wm * 64 + fr * 16 + l4 * 4;
        #pragma unroll
        for (int fc = 0; fc < 4; ++fc) {
            const int colg = n0 + wn * 64 + fc * 16 + l15;
            #pragma unroll
            for (int r = 0; r < 4; ++r) {
                const float v = acc[fr][fc][r] + bv[fc];
                const size_t off = (size_t)(rowg + r) * N + colg;
                if (EPI == 0) ((u16*)Cout)[off] = f2bf(v);
                else          ((u16*)Cout)[off] = f2bf(gelu_f(v));
            }
        }
    }
}

// ---------- merged 2-phase GEMM (R15), BM=256 for MLP1 ----------
template <int BM, int EPI>
__global__ __launch_bounds__(512, 1)
void gemm_pipe_kernel(const u16* __restrict__ A, const u16* __restrict__ Bt,
                      const float* __restrict__ bias, void* __restrict__ Cout,
                      int M, int N, int K)
{
    constexpr int AH  = BM * 64;
    constexpr int BH  = 16384;
    constexpr int BUF = 2 * AH + 2 * BH;
    constexpr int LPA = BM / 128;
    constexpr int GRP = LPA + 2;
    constexpr int MR  = BM / 32;

    extern __shared__ char smem[];

    const int tid  = threadIdx.x;
    const int wid  = tid >> 6, lane = tid & 63;
    const int l15  = lane & 15, l4 = lane >> 4;
    const int wm   = wid >> 2, wn = wid & 3;

    const int nwg = gridDim.x;
    const int qx = nwg >> 3, rx = nwg & 7;
    const int orig = blockIdx.x;
    const int xcd = orig & 7, jx = orig >> 3;
    const int wgid = (xcd < rx ? xcd * (qx + 1) : rx * (qx + 1) + (xcd - rx) * qx) + jx;
    const int NTn = N / 256;
    const int m0 = (wgid / NTn) * BM;
    const int n0 = (wgid % NTn) * 256;

    const int q0 = tid >> 3, g0 = tid & 7;
    const int u0 = g0 ^ (q0 & 7);
    const int r0 = (q0 << 1) | (u0 >> 2), c80 = u0 & 3;
    const int q1 = q0 + 64;
    const int u1 = g0 ^ (q1 & 7);
    const int r1 = (q1 << 1) | (u1 >> 2), c81 = u1 & 3;
    const u16* aP0 = A  + (size_t)(m0 + r0) * K + c80 * 8;
    const u16* aP1 = A  + (size_t)(m0 + r1) * K + c81 * 8;
    const u16* bP0 = Bt + (size_t)(n0 + r0) * K + c80 * 8;
    const u16* bP1 = Bt + (size_t)(n0 + r1) * K + c81 * 8;
    const int NT = K >> 6;
    const int NTm1 = NT - 1;

    auto stageAB = [&](int tt, int kk, int sb) {
        const int kte = (tt << 6) + (kk << 5);
        char* da = smem + sb * BUF + kk * AH + tid * 16;
        gld_lds16(aP0 + kte, da);
        if constexpr (LPA == 2) gld_lds16(aP1 + kte, da + 8192);
        char* db = smem + sb * BUF + 2 * AH + kk * BH + tid * 16;
        gld_lds16(bP0 + kte, db);
        gld_lds16(bP1 + kte, db + 8192);
    };

    auto frag_off = [&](int row) -> int {
        const int q = row >> 1;
        const int u = ((row & 1) << 2) | l4;
        const int g = u ^ (q & 7);
        return q * 128 + g * 16;
    };

    f32x4 acc[MR][4];
    #pragma unroll
    for (int i = 0; i < MR; ++i)
        #pragma unroll
        for (int jj = 0; jj < 4; ++jj) acc[i][jj] = f32x4{0.f, 0.f, 0.f, 0.f};

    stageAB(0, 0, 0); stageAB(0, 1, 0); stageAB(1, 0, 1);
    if constexpr (GRP == 4) asm volatile("s_waitcnt vmcnt(8)" ::: "memory");
    else                    asm volatile("s_waitcnt vmcnt(6)" ::: "memory");
    __builtin_amdgcn_s_barrier();
    asm volatile("" ::: "memory");

    for (int t = 0; t < NT; ++t) {
        const char* buf = smem + (t & 1) * BUF;
        bf16x8 bfr[4], af[MR];

        #pragma unroll
        for (int kk = 0; kk < 2; ++kk) {
            #pragma unroll
            for (int fc = 0; fc < 4; ++fc)
                bfr[fc] = *(const bf16x8*)(buf + 2 * AH + kk * BH +
                                           frag_off(wn * 64 + fc * 16 + l15));
            #pragma unroll
            for (int i = 0; i < MR; ++i)
                af[i] = *(const bf16x8*)(buf + kk * AH +
                                         frag_off(wm * (BM / 2) + i * 16 + l15));
            if (kk == 0) {
                const int tt = (t + 1 <= NTm1) ? t + 1 : NTm1;
                stageAB(tt, 1, (t + 1) & 1);
            } else {
                const int tt = (t + 2 <= NTm1) ? t + 2 : NTm1;
                stageAB(tt, 0, t & 1);
            }
            if constexpr (GRP == 4) asm volatile("s_waitcnt vmcnt(8)" ::: "memory");
            else                    asm volatile("s_waitcnt vmcnt(6)" ::: "memory");
            __builtin_amdgcn_s_barrier();
            asm volatile("" ::: "memory");
            __builtin_amdgcn_s_setprio(1);
            #pragma unroll
            for (int i = 0; i < MR; ++i)
                #pragma unroll
                for (int fc = 0; fc < 4; ++fc)
                    acc[i][fc] = mfma16(af[i], bfr[fc], acc[i][fc]);
            __builtin_amdgcn_s_setprio(0);
            asm volatile("" ::: "memory");
        }
    }

    float bv[4];
    #pragma unroll
    for (int fc = 0; fc < 4; ++fc) bv[fc] = bias[n0 + wn * 64 + fc * 16 + l15];
    #pragma unroll
    for (int fr = 0; fr < MR; ++fr) {
        const int rowg = m0 + wm * (BM / 2) + fr * 16 + l4 * 4;
        #pragma unroll
        for (int fc = 0; fc < 4; ++fc) {
            const int colg = n0 + wn * 64 + fc * 16 + l15;
            #pragma unroll
            for (int r = 0; r < 4; ++r) {
                const float v = acc[fr][fc][r] + bv[fc];
                const size_t off = (size_t)(rowg + r) * N + colg;
                if (EPI == 0) ((u16*)Cout)[off] = f2bf(v);
                else          ((u16*)Cout)[off] = f2bf(gelu_f(v));
            }
        }
    }
}

// ---------- V transpose: qkv[b*2048+s][2048 + h*64+d] -> Vt[bh][d][s] ----------
__global__ __launch_bounds__(256)
void vtrans_kernel(const u16* __restrict__ QKV, u16* __restrict__ Vt) {
    __shared__ u16 tile[64][68];
    const int t  = threadIdx.x;
    const int st = blockIdx.x, bh = blockIdx.y;
    const int b  = bh >> 4, h = bh & 15;
    #pragma unroll
    for (int i = 0; i < 2; ++i) {
        int sl = i * 32 + (t >> 3);
        const u16* gp = QKV + ((size_t)b * 2048 + st * 64 + sl) * 3072 + 2048 + h * 64 + (t & 7) * 8;
        ushort4 a = *(const ushort4*)gp;
        ushort4 c = *(const ushort4*)(gp + 4);
        u16* lp = &tile[sl][(t & 7) * 8];
        *(ushort4*)lp       = a;
        *(ushort4*)(lp + 4) = c;
    }
    __syncthreads();
    #pragma unroll
    for (int i = 0; i < 2; ++i) {
        int d  = i * 32 + (t >> 3);
        int s8 = (t & 7) * 8;
        ushort4 o0, o1;
        o0.x = tile[s8 + 0][d]; o0.y = tile[s8 + 1][d]; o0.z = tile[s8 + 2][d]; o0.w = tile[s8 + 3][d];
        o1.x = tile[s8 + 4][d]; o1.y = tile[s8 + 5][d]; o1.z = tile[s8 + 6][d]; o1.w = tile[s8 + 7][d];
        u16* op = Vt + ((size_t)bh * 64 + d) * 2048 + st * 64 + s8;
        *(ushort4*)op       = o0;
        *(ushort4*)(op + 4) = o1;
    }
}

// ---------- flash attention: QBLK=256, 8 waves; XCD-aligned grid ----------
__global__ __launch_bounds__(512)
void attn_kernel(const u16* __restrict__ QKV, const u16* __restrict__ Vt,
                 u16* __restrict__ ctx)
{
    __shared__ u16 smem[24576];

    const int tid = threadIdx.x;
    const int wid = tid >> 6, lane = tid & 63;
    const int l15 = lane & 15, l4 = lane >> 4;
    const int sw  = l15 & 7;
    const int lr  = lane >> 3;
    const int gsrc = ((lane & 7) ^ lr) * 8;
    const int g   = blockIdx.x;
    const int bh  = (g & 7) | ((g >> 6) << 3);
    const int qt  = (g >> 3) & 7;
    const int b = bh >> 4, h = bh & 15;
    const size_t qrow0 = (size_t)b * 2048 + (size_t)qt * 256;

    u16* const K0 = smem + 16384;
    u16* const V0 = smem + 20480;
    u16* const K1 = smem;
    u16* const V1 = smem + 4096;

    const u16* Qbase = QKV + h * 64;
    const u16* Kbase = QKV + (size_t)b * 2048 * 3072 + 1024 + h * 64;
    const u16* Vbase = Vt + (size_t)bh * 64 * 2048;

    #pragma unroll
    for (int c = 0; c < 4; ++c) {
        const int chunk = wid * 4 + c;
        const int row = chunk * 8 + lr;
        gld_lds16(Qbase + (qrow0 + row) * 3072 + gsrc,
                  (char*)smem + chunk * 1024);
    }

    auto stage_kv = [&](int kt, u16* kb, u16* vb) {
        const int rho = wid * 8 + lr;
        const int krow = (rho & 32) + ((rho & 16) >> 2) + ((rho & 12) << 1) + (rho & 3);
        gld_lds16(Kbase + (size_t)(kt + krow) * 3072 + gsrc,
                  (char*)kb + wid * 1024);
        gld_lds16(Vbase + (size_t)rho * 2048 + kt + gsrc,
                  (char*)vb + wid * 1024);
    };

    stage_kv(0, K0, V0);
    __syncthreads();

    bf16x8 qf[2][2];
    #pragma unroll
    for (int mi = 0; mi < 2; ++mi)
        #pragma unroll
        for (int kk = 0; kk < 2; ++kk)
            qf[mi][kk] = *(const bf16x8*)
                &smem[(size_t)(wid * 32 + mi * 16 + l15) * 64 + (((kk * 4 + l4) ^ sw) * 8)];
    __syncthreads();

    f32x4 accO[2][4] = {};
    f32x4 accL[2] = {};
    const short one_bf = (short)0x3F80;
    const bf16x8 ones = {one_bf, one_bf, one_bf, one_bf,
                         one_bf, one_bf, one_bf, one_bf};

    union U4 { unsigned u[4]; bf16x8 v; };

    auto compute_tile = [&](const u16* kb, const u16* vb) {
        f32x4 st[2][4];
        #pragma unroll
        for (int mi = 0; mi < 2; ++mi)
            #pragma unroll
            for (int ni = 0; ni < 4; ++ni) st[mi][ni] = f32x4{0.f, 0.f, 0.f, 0.f};
        __builtin_amdgcn_s_setprio(1);
        #pragma unroll
        for (int ni = 0; ni < 4; ++ni) {
            bf16x8 kf0 = *(const bf16x8*)&kb[(ni * 16 + l15) * 64 + ((l4 ^ sw) * 8)];
            bf16x8 kf1 = *(const bf16x8*)&kb[(ni * 16 + l15) * 64 + (((4 + l4) ^ sw) * 8)];
            #pragma unroll
            for (int mi = 0; mi < 2; ++mi) {
                st[mi][ni] = mfma16(kf0, qf[mi][0], st[mi][ni]);
                st[mi][ni] = mfma16(kf1, qf[mi][1], st[mi][ni]);
            }
        }
        __builtin_amdgcn_s_setprio(0);

        U4 pb[2][2];
        #pragma unroll
        for (int mi = 0; mi < 2; ++mi) {
            float p[4][4];
            #pragma unroll
            for (int ni = 0; ni < 4; ++ni)
                #pragma unroll
                for (int r = 0; r < 4; ++r)
                    p[ni][r] = fexp2(st[mi][ni][r]);
            #pragma unroll
            for (int ni = 0; ni < 4; ++ni) {
                pb[mi][ni >> 1].u[(ni & 1) * 2 + 0] = cvtpk(p[ni][0], p[ni][1]);
                pb[mi][ni >> 1].u[(ni & 1) * 2 + 1] = cvtpk(p[ni][2], p[ni][3]);
            }
        }

        __builtin_amdgcn_s_setprio(1);
        #pragma unroll
        for (int mi = 0; mi < 2; ++mi) {
            accL[mi] = mfma16(ones, pb[mi][0].v, accL[mi]);
            accL[mi] = mfma16(ones, pb[mi][1].v, accL[mi]);
        }
        #pragma unroll
        for (int di = 0; di < 4; ++di) {
            bf16x8 vf0 = *(const bf16x8*)&vb[(di * 16 + l15) * 64 + ((l4 ^ sw) * 8)];
            bf16x8 vf1 = *(const bf16x8*)&vb[(di * 16 + l15) * 64 + (((4 + l4) ^ sw) * 8)];
            #pragma unroll
            for (int mi = 0; mi < 2; ++mi) {
                accO[mi][di] = mfma16(vf0, pb[mi][0].v, accO[mi][di]);
                accO[mi][di] = mfma16(vf1, pb[mi][1].v, accO[mi][di]);
            }
        }
        __builtin_amdgcn_s_setprio(0);
    };

    for (int it = 0; it < 32; it += 2) {
        if (it + 1 < 32) stage_kv((it + 1) * 64, K1, V1);
        compute_tile(K0, V0);
        __syncthreads();
        if (it + 2 < 32) stage_kv((it + 2) * 64, K0, V0);
        compute_tile(K1, V1);
        __syncthreads();
    }

    #pragma unroll
    for (int mi = 0; mi < 2; ++mi) {
        const float inv = 1.0f / accL[mi][0];
        const size_t q = qrow0 + wid * 32 + mi * 16 + l15;
        #pragma unroll
        for (int di = 0; di < 4; ++di) {
            uint2 w;
            w.x = cvtpk(accO[mi][di][0] * inv, accO[mi][di][1] * inv);
            w.y = cvtpk(accO[mi][di][2] * inv, accO[mi][di][3] * inv);
            *(uint2*)&ctx[q * 1024 + h * 64 + di * 16 + l4 * 4] = w;
        }
    }
}

// ---------- fused add + layernorm; X,Y bf16; outputs f32 and/or bf16 ----------
__global__ __launch_bounds__(256)
void add_ln_kernel(const u16* __restrict__ X, const u16* __restrict__ Y,
                   const float* __restrict__ gamma, const float* __restrict__ beta,
                   float* __restrict__ outf, u16* __restrict__ outb)
{
    const int row = blockIdx.x;
    const int t = threadIdx.x;
    const ushort4 xb = ((const ushort4*)(X + (size_t)row * 1024))[t];
    const ushort4 yb = ((const ushort4*)(Y + (size_t)row * 1024))[t];
    const float v0 = bf2f(xb.x) + bf2f(yb.x);
    const float v1 = bf2f(xb.y) + bf2f(yb.y);
    const float v2 = bf2f(xb.z) + bf2f(yb.z);
    const float v3 = bf2f(xb.w) + bf2f(yb.w);
    float s  = v0 + v1 + v2 + v3;
    float ss = v0 * v0 + v1 * v1 + v2 * v2 + v3 * v3;
    #pragma unroll
    for (int m = 1; m < 64; m <<= 1) {
        s  += __shfl_xor(s, m, 64);
        ss += __shfl_xor(ss, m, 64);
    }
    __shared__ float red[8];
    const int wid = t >> 6, lane = t & 63;
    if (lane == 0) { red[wid] = s; red[4 + wid] = ss; }
    __syncthreads();
    s  = red[0] + red[1] + red[2] + red[3];
    ss = red[4] + red[5] + red[6] + red[7];
    const float mu  = s * (1.f / 1024.f);
    const float var = ss * (1.f / 1024.f) - mu * mu;
    const float inv = rsqrtf(var + 1e-5f);
    const float4 g  = ((const float4*)gamma)[t];
    const float4 bb = ((const float4*)beta)[t];
    float4 o;
    o.x = (v0 - mu) * inv * g.x + bb.x;
    o.y = (v1 - mu) * inv * g.y + bb.y;
    o.z = (v2 - mu) * inv * g.z + bb.z;
    o.w = (v3 - mu) * inv * g.w + bb.w;
    if (outf != nullptr)
        ((float4*)(outf + (size_t)row * 1024))[t] = o;
    if (outb != nullptr) {
        ushort4 ob = make_ushort4(f2bf(o.x), f2bf(o.y), f2bf(o.z), f2bf(o.w));
        ((ushort4*)(outb + (size_t)row * 1024))[t] = ob;
    }
}

// ---------- launcher ----------
extern "C" void kernel_launch(void* const* d_in, const int* in_sizes, int n_in,
                              void* d_out, int out_size, void* d_ws, size_t ws_size,
                              hipStream_t stream)
{
    (void)in_sizes; (void)n_in; (void)out_size; (void)ws_size;
    const float* x   = (const float*)d_in[0];
    const float* Wq  = (const float*)d_in[1];
    const float* bq  = (const float*)d_in[2];
    const float* Wk  = (const float*)d_in[3];
    const float* bk  = (const float*)d_in[4];
    const float* Wv  = (const float*)d_in[5];
    const float* bv  = (const float*)d_in[6];
    const float* Wo  = (const float*)d_in[7];
    const float* bo  = (const float*)d_in[8];
    const float* g1  = (const float*)d_in[9];
    const float* be1 = (const float*)d_in[10];
    const float* W1  = (const float*)d_in[11];
    const float* b1  = (const float*)d_in[12];
    const float* W2  = (const float*)d_in[13];
    const float* b2  = (const float*)d_in[14];
    const float* g2  = (const float*)d_in[15];
    const float* be2 = (const float*)d_in[16];

    constexpr int M = 8192;
    constexpr int D = 1024;
    constexpr int F = 4096;

    char* ws = (char*)d_ws;
    size_t off = 0;
    auto nxt = [&](size_t bytes) -> char* {
        char* p = ws + off;
        off += (bytes + 255) & ~(size_t)255;
        return p;
    };
    u16*   xb    = (u16*)nxt((size_t)M * D * 2);
    u16*   wqkvt = (u16*)nxt((size_t)3 * D * D * 2);
    u16*   wot   = (u16*)nxt((size_t)D * D * 2);
    u16*   w1t   = (u16*)nxt((size_t)F * D * 2);
    u16*   w2t   = (u16*)nxt((size_t)D * F * 2);
    float* bqkv  = (float*)nxt(3072 * 4);
    u16*   qkv   = (u16*)nxt((size_t)M * 3 * D * 2);
    u16*   Vtb   = (u16*)nxt((size_t)M * D * 2);
    u16*   ctx   = (u16*)nxt((size_t)M * D * 2);
    u16*   attn  = (u16*)nxt((size_t)M * D * 2);
    u16*   hb    = (u16*)nxt((size_t)M * D * 2);
    u16*   t1    = qkv;
    u16*   mlp   = attn;

    // 1. merged prepass (weights tcast + x cast), bias concat
    prepass_kernel<<<dim3(16384), dim3(256), 0, stream>>>(
        Wq, Wk, Wv, Wo, W1, W2, x, wqkvt, wot, w1t, w2t, xb);
    bias_concat_kernel<<<dim3(12), dim3(256), 0, stream>>>(bq, bk, bv, bqkv);

    constexpr size_t LDSB32 = 2 * (8192 + 16384);          // 49152 -> 2 blocks/CU (reg-limited)
    constexpr size_t LDS256 = 2 * (2 * 256 * 64 + 2 * 16384);   // 131072

    // 2. fused QKV projection (BK=32, 2 blocks/CU)
    gemm_bk32_kernel<0><<<dim3((M / 128) * (3 * D / 256)), dim3(512), LDSB32, stream>>>(
        xb, wqkvt, bqkv, qkv, M, 3 * D, D);

    // 3. attention (QBLK=256, XCD-aligned 1-D grid)
    vtrans_kernel<<<dim3(2048 / 64, 64), dim3(256), 0, stream>>>(qkv, Vtb);
    attn_kernel<<<dim3(512), dim3(512), 0, stream>>>(qkv, Vtb, ctx);

    // 4. O projection (bf16 out) + LN1 (bf16 residual chain)
    gemm_bk32_kernel<0><<<dim3((M / 128) * (D / 256)), dim3(512), LDSB32, stream>>>(
        ctx, wot, bo, attn, M, D, D);
    add_ln_kernel<<<dim3(M), dim3(256), 0, stream>>>(xb, attn, g1, be1, nullptr, hb);

    // 5. MLP (R15 merged 2-phase BM=256 for MLP1) + LN2
    gemm_pipe_kernel<256, 2><<<dim3((M / 256) * (F / 256)), dim3(512), LDS256, stream>>>(
        hb, w1t, b1, t1, M, F, D);
    gemm_bk32_kernel<0><<<dim3((M / 128) * (D / 256)), dim3(512), LDSB32, stream>>>(
        t1, w2t, b2, mlp, M, D, F);
    add_ln_kernel<<<dim3(M), dim3(256), 0, stream>>>(hb, mlp, g2, be2, (float*)d_out, nullptr);
}

// Round 18
// 355.015 us; speedup vs baseline: 5.6045x; 1.0254x over previous
//
#include <hip/hip_runtime.h>
#include <cstdint>
#include <cstddef>

using u16 = unsigned short;
using bf16x8 = __attribute__((ext_vector_type(8))) short;
using f32x4  = __attribute__((ext_vector_type(4))) float;

// ---------- helpers ----------
__device__ __forceinline__ u16 f2bf(float f) {
    union { float f; unsigned u; } v; v.f = f;
    unsigned r = v.u + 0x7fffu + ((v.u >> 16) & 1u);   // RNE
    return (u16)(r >> 16);
}

__device__ __forceinline__ float bf2f(u16 b) {
    union { unsigned u; float f; } v; v.u = (unsigned)b << 16;
    return v.f;
}

__device__ __forceinline__ unsigned cvtpk(float lo, float hi) {
    unsigned r;
    asm("v_cvt_pk_bf16_f32 %0, %1, %2" : "=v"(r) : "v"(lo), "v"(hi));
    return r;
}

// raw v_exp_f32: D = 2^S0 (native TRANS op)
__device__ __forceinline__ float fexp2(float x) {
    float r;
    asm("v_exp_f32 %0, %1" : "=v"(r) : "v"(x));
    return r;
}

// tanh-form GELU via native exp2
__device__ __forceinline__ float gelu_f(float x) {
    const float t2 = fminf(x * fmaf(0.10294825f, x * x, 2.3022082f), 80.f);
    const float e  = fexp2(t2);
    return x * e * __frcp_rn(e + 1.0f);
}

__device__ __forceinline__ void gld_lds16(const void* g, void* l) {
    __builtin_amdgcn_global_load_lds(
        (__attribute__((address_space(1))) void*)g,
        (__attribute__((address_space(3))) void*)l, 16, 0, 0);
}

__device__ __forceinline__ f32x4 mfma16(bf16x8 a, bf16x8 b, f32x4 c) {
    return __builtin_amdgcn_mfma_f32_16x16x32_bf16(a, b, c, 0, 0, 0);
}

// ---------- merged prepass: 6 weight transposes + x cast + bias concat ----------
// blocks [0,12288): weight tcast; [12288,16384): x cast; 16384: bias concat
__global__ __launch_bounds__(256)
void prepass_kernel(const float* __restrict__ Wq, const float* __restrict__ Wk,
                    const float* __restrict__ Wv, const float* __restrict__ Wo,
                    const float* __restrict__ W1, const float* __restrict__ W2,
                    const float* __restrict__ x,
                    const float* __restrict__ bq, const float* __restrict__ bk,
                    const float* __restrict__ bv,
                    u16* __restrict__ wqkvt, u16* __restrict__ wot,
                    u16* __restrict__ w1t, u16* __restrict__ w2t,
                    u16* __restrict__ xb, float* __restrict__ bqkv)
{
    const int g = blockIdx.x;
    if (g == 16384) {
        #pragma unroll
        for (int j = 0; j < 12; ++j) {
            const int i = j * 256 + threadIdx.x;
            float v;
            if (i < 1024)      v = bq[i] * 0.18033688011112042f;   // 0.125*log2e
            else if (i < 2048) v = bk[i - 1024];
            else               v = bv[i - 2048];
            bqkv[i] = v;
        }
        return;
    }
    if (g >= 12288) {
        const int i = (g - 12288) * 256 + threadIdx.x;
        const float4* p = (const float4*)x;
        float4 a = p[i * 2], b = p[i * 2 + 1];
        ushort4 r0 = make_ushort4(f2bf(a.x), f2bf(a.y), f2bf(a.z), f2bf(a.w));
        ushort4 r1 = make_ushort4(f2bf(b.x), f2bf(b.y), f2bf(b.z), f2bf(b.w));
        ((ushort4*)xb)[i * 2]     = r0;
        ((ushort4*)xb)[i * 2 + 1] = r1;
        return;
    }
    const float* src; u16* dst; int K, N, ti; float scale = 1.0f;
    if (g < 1024)      { src = Wq; dst = wqkvt;               K = 1024; N = 1024; ti = g;        scale = 0.18033688011112042f; }
    else if (g < 2048) { src = Wk; dst = wqkvt + 1048576;     K = 1024; N = 1024; ti = g - 1024; }
    else if (g < 3072) { src = Wv; dst = wqkvt + 2097152;     K = 1024; N = 1024; ti = g - 2048; }
    else if (g < 4096) { src = Wo; dst = wot;                 K = 1024; N = 1024; ti = g - 3072; }
    else if (g < 8192) { src = W1; dst = w1t;                 K = 1024; N = 4096; ti = g - 4096; }
    else               { src = W2; dst = w2t;                 K = 4096; N = 1024; ti = g - 8192; }
    const int nt = N >> 5;
    const int bx = ti % nt, by = ti / nt;
    const int k0 = by * 32, n0 = bx * 32;

    __shared__ float tile[32][33];
    const int tx = threadIdx.x & 31, ty = threadIdx.x >> 5;
    #pragma unroll
    for (int r = 0; r < 4; ++r) {
        int k = ty * 4 + r;
        tile[k][tx] = src[(size_t)(k0 + k) * N + n0 + tx];
    }
    __syncthreads();
    const int kx = (threadIdx.x & 15) * 2;
    const int ny = threadIdx.x >> 4;
    #pragma unroll
    for (int r = 0; r < 2; ++r) {
        const int n = ny * 2 + r;
        ushort2 o = make_ushort2(f2bf(tile[kx][n] * scale),
                                 f2bf(tile[kx + 1][n] * scale));
        *(ushort2*)&dst[(size_t)(n0 + n) * K + k0 + kx] = o;
    }
}

// ---------- merged 2-phase counted-vmcnt GEMM (R15 structure, measured best) ----------
// BN=256, 512 threads (8 waves, 2M x 4N), BK=64 in two kk-halves, 2 LDS bufs.
// Per K-tile: TWO phases (one per kk), each = { ds_read ALL MR A-frags + 4
// B-frags | stage one (A+B) kk-group 3-deep ahead | vmcnt(2*GRP) | barrier |
// MR*4 MFMA }. n-major block mapping (A-panel XCD reuse); line-XOR LDS layout.
// EPI: 0 = bf16, 2 = GELU->bf16
template <int BM, int EPI>
__global__ __launch_bounds__(512, 1)
void gemm_pipe_kernel(const u16* __restrict__ A, const u16* __restrict__ Bt,
                      const float* __restrict__ bias, void* __restrict__ Cout,
                      int M, int N, int K)
{
    constexpr int AH  = BM * 64;
    constexpr int BH  = 16384;
    constexpr int BUF = 2 * AH + 2 * BH;
    constexpr int LPA = BM / 128;
    constexpr int GRP = LPA + 2;
    constexpr int MR  = BM / 32;

    extern __shared__ char smem[];

    const int tid  = threadIdx.x;
    const int wid  = tid >> 6, lane = tid & 63;
    const int l15  = lane & 15, l4 = lane >> 4;
    const int wm   = wid >> 2, wn = wid & 3;

    const int nwg = gridDim.x;
    const int qx = nwg >> 3, rx = nwg & 7;
    const int orig = blockIdx.x;
    const int xcd = orig & 7, jx = orig >> 3;
    const int wgid = (xcd < rx ? xcd * (qx + 1) : rx * (qx + 1) + (xcd - rx) * qx) + jx;
    const int NTn = N / 256;
    const int m0 = (wgid / NTn) * BM;
    const int n0 = (wgid % NTn) * 256;

    const int q0 = tid >> 3, g0 = tid & 7;
    const int u0 = g0 ^ (q0 & 7);
    const int r0 = (q0 << 1) | (u0 >> 2), c80 = u0 & 3;
    const int q1 = q0 + 64;
    const int u1 = g0 ^ (q1 & 7);
    const int r1 = (q1 << 1) | (u1 >> 2), c81 = u1 & 3;
    const u16* aP0 = A  + (size_t)(m0 + r0) * K + c80 * 8;
    const u16* aP1 = A  + (size_t)(m0 + r1) * K + c81 * 8;
    const u16* bP0 = Bt + (size_t)(n0 + r0) * K + c80 * 8;
    const u16* bP1 = Bt + (size_t)(n0 + r1) * K + c81 * 8;
    const int NT = K >> 6;
    const int NTm1 = NT - 1;

    auto stageAB = [&](int tt, int kk, int sb) {
        const int kte = (tt << 6) + (kk << 5);
        char* da = smem + sb * BUF + kk * AH + tid * 16;
        gld_lds16(aP0 + kte, da);
        if constexpr (LPA == 2) gld_lds16(aP1 + kte, da + 8192);
        char* db = smem + sb * BUF + 2 * AH + kk * BH + tid * 16;
        gld_lds16(bP0 + kte, db);
        gld_lds16(bP1 + kte, db + 8192);
    };

    auto frag_off = [&](int row) -> int {
        const int q = row >> 1;
        const int u = ((row & 1) << 2) | l4;
        const int g = u ^ (q & 7);
        return q * 128 + g * 16;
    };

    f32x4 acc[MR][4];
    #pragma unroll
    for (int i = 0; i < MR; ++i)
        #pragma unroll
        for (int jj = 0; jj < 4; ++jj) acc[i][jj] = f32x4{0.f, 0.f, 0.f, 0.f};

    stageAB(0, 0, 0); stageAB(0, 1, 0); stageAB(1, 0, 1);
    if constexpr (GRP == 4) asm volatile("s_waitcnt vmcnt(8)" ::: "memory");
    else                    asm volatile("s_waitcnt vmcnt(6)" ::: "memory");
    __builtin_amdgcn_s_barrier();
    asm volatile("" ::: "memory");

    for (int t = 0; t < NT; ++t) {
        const char* buf = smem + (t & 1) * BUF;
        bf16x8 bfr[4], af[MR];

        #pragma unroll
        for (int kk = 0; kk < 2; ++kk) {
            #pragma unroll
            for (int fc = 0; fc < 4; ++fc)
                bfr[fc] = *(const bf16x8*)(buf + 2 * AH + kk * BH +
                                           frag_off(wn * 64 + fc * 16 + l15));
            #pragma unroll
            for (int i = 0; i < MR; ++i)
                af[i] = *(const bf16x8*)(buf + kk * AH +
                                         frag_off(wm * (BM / 2) + i * 16 + l15));
            if (kk == 0) {
                const int tt = (t + 1 <= NTm1) ? t + 1 : NTm1;
                stageAB(tt, 1, (t + 1) & 1);
            } else {
                const int tt = (t + 2 <= NTm1) ? t + 2 : NTm1;
                stageAB(tt, 0, t & 1);
            }
            if constexpr (GRP == 4) asm volatile("s_waitcnt vmcnt(8)" ::: "memory");
            else                    asm volatile("s_waitcnt vmcnt(6)" ::: "memory");
            __builtin_amdgcn_s_barrier();
            asm volatile("" ::: "memory");
            __builtin_amdgcn_s_setprio(1);
            #pragma unroll
            for (int i = 0; i < MR; ++i)
                #pragma unroll
                for (int fc = 0; fc < 4; ++fc)
                    acc[i][fc] = mfma16(af[i], bfr[fc], acc[i][fc]);
            __builtin_amdgcn_s_setprio(0);
            asm volatile("" ::: "memory");
        }
    }

    float bv[4];
    #pragma unroll
    for (int fc = 0; fc < 4; ++fc) bv[fc] = bias[n0 + wn * 64 + fc * 16 + l15];
    #pragma unroll
    for (int fr = 0; fr < MR; ++fr) {
        const int rowg = m0 + wm * (BM / 2) + fr * 16 + l4 * 4;
        #pragma unroll
        for (int fc = 0; fc < 4; ++fc) {
            const int colg = n0 + wn * 64 + fc * 16 + l15;
            #pragma unroll
            for (int r = 0; r < 4; ++r) {
                const float v = acc[fr][fc][r] + bv[fc];
                const size_t off = (size_t)(rowg + r) * N + colg;
                if (EPI == 0) ((u16*)Cout)[off] = f2bf(v);
                else          ((u16*)Cout)[off] = f2bf(gelu_f(v));
            }
        }
    }
}

// ---------- V transpose: qkv[b*2048+s][2048 + h*64+d] -> Vt[bh][d][s] ----------
__global__ __launch_bounds__(256)
void vtrans_kernel(const u16* __restrict__ QKV, u16* __restrict__ Vt) {
    __shared__ u16 tile[64][68];
    const int t  = threadIdx.x;
    const int st = blockIdx.x, bh = blockIdx.y;
    const int b  = bh >> 4, h = bh & 15;
    #pragma unroll
    for (int i = 0; i < 2; ++i) {
        int sl = i * 32 + (t >> 3);
        const u16* gp = QKV + ((size_t)b * 2048 + st * 64 + sl) * 3072 + 2048 + h * 64 + (t & 7) * 8;
        ushort4 a = *(const ushort4*)gp;
        ushort4 c = *(const ushort4*)(gp + 4);
        u16* lp = &tile[sl][(t & 7) * 8];
        *(ushort4*)lp       = a;
        *(ushort4*)(lp + 4) = c;
    }
    __syncthreads();
    #pragma unroll
    for (int i = 0; i < 2; ++i) {
        int d  = i * 32 + (t >> 3);
        int s8 = (t & 7) * 8;
        ushort4 o0, o1;
        o0.x = tile[s8 + 0][d]; o0.y = tile[s8 + 1][d]; o0.z = tile[s8 + 2][d]; o0.w = tile[s8 + 3][d];
        o1.x = tile[s8 + 4][d]; o1.y = tile[s8 + 5][d]; o1.z = tile[s8 + 6][d]; o1.w = tile[s8 + 7][d];
        u16* op = Vt + ((size_t)bh * 64 + d) * 2048 + st * 64 + s8;
        *(ushort4*)op       = o0;
        *(ushort4*)(op + 4) = o1;
    }
}

// ---------- flash attention: QBLK=256, 8 waves; XCD-aligned grid ----------
__global__ __launch_bounds__(512)
void attn_kernel(const u16* __restrict__ QKV, const u16* __restrict__ Vt,
                 u16* __restrict__ ctx)
{
    __shared__ u16 smem[24576];

    const int tid = threadIdx.x;
    const int wid = tid >> 6, lane = tid & 63;
    const int l15 = lane & 15, l4 = lane >> 4;
    const int sw  = l15 & 7;
    const int lr  = lane >> 3;
    const int gsrc = ((lane & 7) ^ lr) * 8;
    const int g   = blockIdx.x;
    const int bh  = (g & 7) | ((g >> 6) << 3);
    const int qt  = (g >> 3) & 7;
    const int b = bh >> 4, h = bh & 15;
    const size_t qrow0 = (size_t)b * 2048 + (size_t)qt * 256;

    u16* const K0 = smem + 16384;
    u16* const V0 = smem + 20480;
    u16* const K1 = smem;
    u16* const V1 = smem + 4096;

    const u16* Qbase = QKV + h * 64;
    const u16* Kbase = QKV + (size_t)b * 2048 * 3072 + 1024 + h * 64;
    const u16* Vbase = Vt + (size_t)bh * 64 * 2048;

    #pragma unroll
    for (int c = 0; c < 4; ++c) {
        const int chunk = wid * 4 + c;
        const int row = chunk * 8 + lr;
        gld_lds16(Qbase + (qrow0 + row) * 3072 + gsrc,
                  (char*)smem + chunk * 1024);
    }

    auto stage_kv = [&](int kt, u16* kb, u16* vb) {
        const int rho = wid * 8 + lr;
        const int krow = (rho & 32) + ((rho & 16) >> 2) + ((rho & 12) << 1) + (rho & 3);
        gld_lds16(Kbase + (size_t)(kt + krow) * 3072 + gsrc,
                  (char*)kb + wid * 1024);
        gld_lds16(Vbase + (size_t)rho * 2048 + kt + gsrc,
                  (char*)vb + wid * 1024);
    };

    stage_kv(0, K0, V0);
    __syncthreads();

    bf16x8 qf[2][2];
    #pragma unroll
    for (int mi = 0; mi < 2; ++mi)
        #pragma unroll
        for (int kk = 0; kk < 2; ++kk)
            qf[mi][kk] = *(const bf16x8*)
                &smem[(size_t)(wid * 32 + mi * 16 + l15) * 64 + (((kk * 4 + l4) ^ sw) * 8)];
    __syncthreads();

    f32x4 accO[2][4] = {};
    f32x4 accL[2] = {};
    const short one_bf = (short)0x3F80;
    const bf16x8 ones = {one_bf, one_bf, one_bf, one_bf,
                         one_bf, one_bf, one_bf, one_bf};

    union U4 { unsigned u[4]; bf16x8 v; };

    auto compute_tile = [&](const u16* kb, const u16* vb) {
        f32x4 st[2][4];
        #pragma unroll
        for (int mi = 0; mi < 2; ++mi)
            #pragma unroll
            for (int ni = 0; ni < 4; ++ni) st[mi][ni] = f32x4{0.f, 0.f, 0.f, 0.f};
        __builtin_amdgcn_s_setprio(1);
        #pragma unroll
        for (int ni = 0; ni < 4; ++ni) {
            bf16x8 kf0 = *(const bf16x8*)&kb[(ni * 16 + l15) * 64 + ((l4 ^ sw) * 8)];
            bf16x8 kf1 = *(const bf16x8*)&kb[(ni * 16 + l15) * 64 + (((4 + l4) ^ sw) * 8)];
            #pragma unroll
            for (int mi = 0; mi < 2; ++mi) {
                st[mi][ni] = mfma16(kf0, qf[mi][0], st[mi][ni]);
                st[mi][ni] = mfma16(kf1, qf[mi][1], st[mi][ni]);
            }
        }
        __builtin_amdgcn_s_setprio(0);

        U4 pb[2][2];
        #pragma unroll
        for (int mi = 0; mi < 2; ++mi) {
            float p[4][4];
            #pragma unroll
            for (int ni = 0; ni < 4; ++ni)
                #pragma unroll
                for (int r = 0; r < 4; ++r)
                    p[ni][r] = fexp2(st[mi][ni][r]);
            #pragma unroll
            for (int ni = 0; ni < 4; ++ni) {
                pb[mi][ni >> 1].u[(ni & 1) * 2 + 0] = cvtpk(p[ni][0], p[ni][1]);
                pb[mi][ni >> 1].u[(ni & 1) * 2 + 1] = cvtpk(p[ni][2], p[ni][3]);
            }
        }

        __builtin_amdgcn_s_setprio(1);
        #pragma unroll
        for (int mi = 0; mi < 2; ++mi) {
            accL[mi] = mfma16(ones, pb[mi][0].v, accL[mi]);
            accL[mi] = mfma16(ones, pb[mi][1].v, accL[mi]);
        }
        #pragma unroll
        for (int di = 0; di < 4; ++di) {
            bf16x8 vf0 = *(const bf16x8*)&vb[(di * 16 + l15) * 64 + ((l4 ^ sw) * 8)];
            bf16x8 vf1 = *(const bf16x8*)&vb[(di * 16 + l15) * 64 + (((4 + l4) ^ sw) * 8)];
            #pragma unroll
            for (int mi = 0; mi < 2; ++mi) {
                accO[mi][di] = mfma16(vf0, pb[mi][0].v, accO[mi][di]);
                accO[mi][di] = mfma16(vf1, pb[mi][1].v, accO[mi][di]);
            }
        }
        __builtin_amdgcn_s_setprio(0);
    };

    for (int it = 0; it < 32; it += 2) {
        if (it + 1 < 32) stage_kv((it + 1) * 64, K1, V1);
        compute_tile(K0, V0);
        __syncthreads();
        if (it + 2 < 32) stage_kv((it + 2) * 64, K0, V0);
        compute_tile(K1, V1);
        __syncthreads();
    }

    #pragma unroll
    for (int mi = 0; mi < 2; ++mi) {
        const float inv = 1.0f / accL[mi][0];
        const size_t q = qrow0 + wid * 32 + mi * 16 + l15;
        #pragma unroll
        for (int di = 0; di < 4; ++di) {
            uint2 w;
            w.x = cvtpk(accO[mi][di][0] * inv, accO[mi][di][1] * inv);
            w.y = cvtpk(accO[mi][di][2] * inv, accO[mi][di][3] * inv);
            *(uint2*)&ctx[q * 1024 + h * 64 + di * 16 + l4 * 4] = w;
        }
    }
}

// ---------- fused add + layernorm; X,Y bf16; outputs f32 and/or bf16 ----------
__global__ __launch_bounds__(256)
void add_ln_kernel(const u16* __restrict__ X, const u16* __restrict__ Y,
                   const float* __restrict__ gamma, const float* __restrict__ beta,
                   float* __restrict__ outf, u16* __restrict__ outb)
{
    const int row = blockIdx.x;
    const int t = threadIdx.x;
    const ushort4 xb = ((const ushort4*)(X + (size_t)row * 1024))[t];
    const ushort4 yb = ((const ushort4*)(Y + (size_t)row * 1024))[t];
    const float v0 = bf2f(xb.x) + bf2f(yb.x);
    const float v1 = bf2f(xb.y) + bf2f(yb.y);
    const float v2 = bf2f(xb.z) + bf2f(yb.z);
    const float v3 = bf2f(xb.w) + bf2f(yb.w);
    float s  = v0 + v1 + v2 + v3;
    float ss = v0 * v0 + v1 * v1 + v2 * v2 + v3 * v3;
    #pragma unroll
    for (int m = 1; m < 64; m <<= 1) {
        s  += __shfl_xor(s, m, 64);
        ss += __shfl_xor(ss, m, 64);
    }
    __shared__ float red[8];
    const int wid = t >> 6, lane = t & 63;
    if (lane == 0) { red[wid] = s; red[4 + wid] = ss; }
    __syncthreads();
    s  = red[0] + red[1] + red[2] + red[3];
    ss = red[4] + red[5] + red[6] + red[7];
    const float mu  = s * (1.f / 1024.f);
    const float var = ss * (1.f / 1024.f) - mu * mu;
    const float inv = rsqrtf(var + 1e-5f);
    const float4 g  = ((const float4*)gamma)[t];
    const float4 bb = ((const float4*)beta)[t];
    float4 o;
    o.x = (v0 - mu) * inv * g.x + bb.x;
    o.y = (v1 - mu) * inv * g.y + bb.y;
    o.z = (v2 - mu) * inv * g.z + bb.z;
    o.w = (v3 - mu) * inv * g.w + bb.w;
    if (outf != nullptr)
        ((float4*)(outf + (size_t)row * 1024))[t] = o;
    if (outb != nullptr) {
        ushort4 ob = make_ushort4(f2bf(o.x), f2bf(o.y), f2bf(o.z), f2bf(o.w));
        ((ushort4*)(outb + (size_t)row * 1024))[t] = ob;
    }
}

// ---------- launcher ----------
extern "C" void kernel_launch(void* const* d_in, const int* in_sizes, int n_in,
                              void* d_out, int out_size, void* d_ws, size_t ws_size,
                              hipStream_t stream)
{
    (void)in_sizes; (void)n_in; (void)out_size; (void)ws_size;
    const float* x   = (const float*)d_in[0];
    const float* Wq  = (const float*)d_in[1];
    const float* bq  = (const float*)d_in[2];
    const float* Wk  = (const float*)d_in[3];
    const float* bk  = (const float*)d_in[4];
    const float* Wv  = (const float*)d_in[5];
    const float* bv  = (const float*)d_in[6];
    const float* Wo  = (const float*)d_in[7];
    const float* bo  = (const float*)d_in[8];
    const float* g1  = (const float*)d_in[9];
    const float* be1 = (const float*)d_in[10];
    const float* W1  = (const float*)d_in[11];
    const float* b1  = (const float*)d_in[12];
    const float* W2  = (const float*)d_in[13];
    const float* b2  = (const float*)d_in[14];
    const float* g2  = (const float*)d_in[15];
    const float* be2 = (const float*)d_in[16];

    constexpr int M = 8192;
    constexpr int D = 1024;
    constexpr int F = 4096;

    char* ws = (char*)d_ws;
    size_t off = 0;
    auto nxt = [&](size_t bytes) -> char* {
        char* p = ws + off;
        off += (bytes + 255) & ~(size_t)255;
        return p;
    };
    u16*   xb    = (u16*)nxt((size_t)M * D * 2);
    u16*   wqkvt = (u16*)nxt((size_t)3 * D * D * 2);
    u16*   wot   = (u16*)nxt((size_t)D * D * 2);
    u16*   w1t   = (u16*)nxt((size_t)F * D * 2);
    u16*   w2t   = (u16*)nxt((size_t)D * F * 2);
    float* bqkv  = (float*)nxt(3072 * 4);
    u16*   qkv   = (u16*)nxt((size_t)M * 3 * D * 2);
    u16*   Vtb   = (u16*)nxt((size_t)M * D * 2);
    u16*   ctx   = (u16*)nxt((size_t)M * D * 2);
    u16*   attn  = (u16*)nxt((size_t)M * D * 2);
    u16*   hb    = (u16*)nxt((size_t)M * D * 2);
    u16*   t1    = qkv;
    u16*   mlp   = attn;

    // 1. merged prepass (weights tcast + x cast + bias concat)
    prepass_kernel<<<dim3(16385), dim3(256), 0, stream>>>(
        Wq, Wk, Wv, Wo, W1, W2, x, bq, bk, bv, wqkvt, wot, w1t, w2t, xb, bqkv);

    constexpr size_t LDS128 = 2 * (2 * 128 * 64 + 2 * 16384);   //  98304
    constexpr size_t LDS256 = 2 * (2 * 256 * 64 + 2 * 16384);   // 131072

    // 2. fused QKV projection (768 blocks = 3 rounds)
    gemm_pipe_kernel<128, 0><<<dim3((M / 128) * (3 * D / 256)), dim3(512), LDS128, stream>>>(
        xb, wqkvt, bqkv, qkv, M, 3 * D, D);

    // 3. attention (QBLK=256, XCD-aligned 1-D grid)
    vtrans_kernel<<<dim3(2048 / 64, 64), dim3(256), 0, stream>>>(qkv, Vtb);
    attn_kernel<<<dim3(512), dim3(512), 0, stream>>>(qkv, Vtb, ctx);

    // 4. O projection (bf16 out) + LN1 (bf16 residual chain)
    gemm_pipe_kernel<128, 0><<<dim3((M / 128) * (D / 256)), dim3(512), LDS128, stream>>>(
        ctx, wot, bo, attn, M, D, D);
    add_ln_kernel<<<dim3(M), dim3(256), 0, stream>>>(xb, attn, g1, be1, nullptr, hb);

    // 5. MLP (256^2 tile for MLP1) + LN2
    gemm_pipe_kernel<256, 2><<<dim3((M / 256) * (F / 256)), dim3(512), LDS256, stream>>>(
        hb, w1t, b1, t1, M, F, D);
    gemm_pipe_kernel<128, 0><<<dim3((M / 128) * (D / 256)), dim3(512), LDS128, stream>>>(
        t1, w2t, b2, mlp, M, D, F);
    add_ln_kernel<<<dim3(M), dim3(256), 0, stream>>>(hb, mlp, g2, be2, (float*)d_out, nullptr);
}

// Round 19
// 348.856 us; speedup vs baseline: 5.7034x; 1.0177x over previous
//
#include <hip/hip_runtime.h>
#include <cstdint>
#include <cstddef>

using u16 = unsigned short;
using bf16x8 = __attribute__((ext_vector_type(8))) short;
using f32x4  = __attribute__((ext_vector_type(4))) float;

// ---------- helpers ----------
__device__ __forceinline__ u16 f2bf(float f) {
    union { float f; unsigned u; } v; v.f = f;
    unsigned r = v.u + 0x7fffu + ((v.u >> 16) & 1u);   // RNE
    return (u16)(r >> 16);
}

__device__ __forceinline__ float bf2f(u16 b) {
    union { unsigned u; float f; } v; v.u = (unsigned)b << 16;
    return v.f;
}

__device__ __forceinline__ unsigned cvtpk(float lo, float hi) {
    unsigned r;
    asm("v_cvt_pk_bf16_f32 %0, %1, %2" : "=v"(r) : "v"(lo), "v"(hi));
    return r;
}

// raw v_exp_f32: D = 2^S0 (native TRANS op)
__device__ __forceinline__ float fexp2(float x) {
    float r;
    asm("v_exp_f32 %0, %1" : "=v"(r) : "v"(x));
    return r;
}

// tanh-form GELU via native exp2
__device__ __forceinline__ float gelu_f(float x) {
    const float t2 = fminf(x * fmaf(0.10294825f, x * x, 2.3022082f), 80.f);
    const float e  = fexp2(t2);
    return x * e * __frcp_rn(e + 1.0f);
}

__device__ __forceinline__ void gld_lds16(const void* g, void* l) {
    __builtin_amdgcn_global_load_lds(
        (__attribute__((address_space(1))) void*)g,
        (__attribute__((address_space(3))) void*)l, 16, 0, 0);
}

__device__ __forceinline__ f32x4 mfma16(bf16x8 a, bf16x8 b, f32x4 c) {
    return __builtin_amdgcn_mfma_f32_16x16x32_bf16(a, b, c, 0, 0, 0);
}

// ---------- merged prepass: 6 weight transposes + x cast + bias concat ----------
__global__ __launch_bounds__(256)
void prepass_kernel(const float* __restrict__ Wq, const float* __restrict__ Wk,
                    const float* __restrict__ Wv, const float* __restrict__ Wo,
                    const float* __restrict__ W1, const float* __restrict__ W2,
                    const float* __restrict__ x,
                    const float* __restrict__ bq, const float* __restrict__ bk,
                    const float* __restrict__ bv,
                    u16* __restrict__ wqkvt, u16* __restrict__ wot,
                    u16* __restrict__ w1t, u16* __restrict__ w2t,
                    u16* __restrict__ xb, float* __restrict__ bqkv)
{
    const int g = blockIdx.x;
    if (g == 16384) {
        #pragma unroll
        for (int j = 0; j < 12; ++j) {
            const int i = j * 256 + threadIdx.x;
            float v;
            if (i < 1024)      v = bq[i] * 0.18033688011112042f;   // 0.125*log2e
            else if (i < 2048) v = bk[i - 1024];
            else               v = bv[i - 2048];
            bqkv[i] = v;
        }
        return;
    }
    if (g >= 12288) {
        const int i = (g - 12288) * 256 + threadIdx.x;
        const float4* p = (const float4*)x;
        float4 a = p[i * 2], b = p[i * 2 + 1];
        ushort4 r0 = make_ushort4(f2bf(a.x), f2bf(a.y), f2bf(a.z), f2bf(a.w));
        ushort4 r1 = make_ushort4(f2bf(b.x), f2bf(b.y), f2bf(b.z), f2bf(b.w));
        ((ushort4*)xb)[i * 2]     = r0;
        ((ushort4*)xb)[i * 2 + 1] = r1;
        return;
    }
    const float* src; u16* dst; int K, N, ti; float scale = 1.0f;
    if (g < 1024)      { src = Wq; dst = wqkvt;               K = 1024; N = 1024; ti = g;        scale = 0.18033688011112042f; }
    else if (g < 2048) { src = Wk; dst = wqkvt + 1048576;     K = 1024; N = 1024; ti = g - 1024; }
    else if (g < 3072) { src = Wv; dst = wqkvt + 2097152;     K = 1024; N = 1024; ti = g - 2048; }
    else if (g < 4096) { src = Wo; dst = wot;                 K = 1024; N = 1024; ti = g - 3072; }
    else if (g < 8192) { src = W1; dst = w1t;                 K = 1024; N = 4096; ti = g - 4096; }
    else               { src = W2; dst = w2t;                 K = 4096; N = 1024; ti = g - 8192; }
    const int nt = N >> 5;
    const int bx = ti % nt, by = ti / nt;
    const int k0 = by * 32, n0 = bx * 32;

    __shared__ float tile[32][33];
    const int tx = threadIdx.x & 31, ty = threadIdx.x >> 5;
    #pragma unroll
    for (int r = 0; r < 4; ++r) {
        int k = ty * 4 + r;
        tile[k][tx] = src[(size_t)(k0 + k) * N + n0 + tx];
    }
    __syncthreads();
    const int kx = (threadIdx.x & 15) * 2;
    const int ny = threadIdx.x >> 4;
    #pragma unroll
    for (int r = 0; r < 2; ++r) {
        const int n = ny * 2 + r;
        ushort2 o = make_ushort2(f2bf(tile[kx][n] * scale),
                                 f2bf(tile[kx + 1][n] * scale));
        *(ushort2*)&dst[(size_t)(n0 + n) * K + k0 + kx] = o;
    }
}

// ---------- merged 2-phase counted-vmcnt GEMM (R15 structure, measured best) ----------
// EPI: 0 = bf16, 2 = GELU->bf16, 3 = QKV (V-blocks n0>=2048 write Vt[bh][d][s]
// directly — r=0..3 are consecutive s positions -> one packed 8B store/frag)
template <int BM, int EPI>
__global__ __launch_bounds__(512, 1)
void gemm_pipe_kernel(const u16* __restrict__ A, const u16* __restrict__ Bt,
                      const float* __restrict__ bias, void* __restrict__ Cout,
                      u16* __restrict__ VtOut,
                      int M, int N, int K)
{
    constexpr int AH  = BM * 64;
    constexpr int BH  = 16384;
    constexpr int BUF = 2 * AH + 2 * BH;
    constexpr int LPA = BM / 128;
    constexpr int GRP = LPA + 2;
    constexpr int MR  = BM / 32;

    extern __shared__ char smem[];

    const int tid  = threadIdx.x;
    const int wid  = tid >> 6, lane = tid & 63;
    const int l15  = lane & 15, l4 = lane >> 4;
    const int wm   = wid >> 2, wn = wid & 3;

    const int nwg = gridDim.x;
    const int qx = nwg >> 3, rx = nwg & 7;
    const int orig = blockIdx.x;
    const int xcd = orig & 7, jx = orig >> 3;
    const int wgid = (xcd < rx ? xcd * (qx + 1) : rx * (qx + 1) + (xcd - rx) * qx) + jx;
    const int NTn = N / 256;
    const int m0 = (wgid / NTn) * BM;
    const int n0 = (wgid % NTn) * 256;

    const int q0 = tid >> 3, g0 = tid & 7;
    const int u0 = g0 ^ (q0 & 7);
    const int r0 = (q0 << 1) | (u0 >> 2), c80 = u0 & 3;
    const int q1 = q0 + 64;
    const int u1 = g0 ^ (q1 & 7);
    const int r1 = (q1 << 1) | (u1 >> 2), c81 = u1 & 3;
    const u16* aP0 = A  + (size_t)(m0 + r0) * K + c80 * 8;
    const u16* aP1 = A  + (size_t)(m0 + r1) * K + c81 * 8;
    const u16* bP0 = Bt + (size_t)(n0 + r0) * K + c80 * 8;
    const u16* bP1 = Bt + (size_t)(n0 + r1) * K + c81 * 8;
    const int NT = K >> 6;
    const int NTm1 = NT - 1;

    auto stageAB = [&](int tt, int kk, int sb) {
        const int kte = (tt << 6) + (kk << 5);
        char* da = smem + sb * BUF + kk * AH + tid * 16;
        gld_lds16(aP0 + kte, da);
        if constexpr (LPA == 2) gld_lds16(aP1 + kte, da + 8192);
        char* db = smem + sb * BUF + 2 * AH + kk * BH + tid * 16;
        gld_lds16(bP0 + kte, db);
        gld_lds16(bP1 + kte, db + 8192);
    };

    auto frag_off = [&](int row) -> int {
        const int q = row >> 1;
        const int u = ((row & 1) << 2) | l4;
        const int g = u ^ (q & 7);
        return q * 128 + g * 16;
    };

    f32x4 acc[MR][4];
    #pragma unroll
    for (int i = 0; i < MR; ++i)
        #pragma unroll
        for (int jj = 0; jj < 4; ++jj) acc[i][jj] = f32x4{0.f, 0.f, 0.f, 0.f};

    stageAB(0, 0, 0); stageAB(0, 1, 0); stageAB(1, 0, 1);
    if constexpr (GRP == 4) asm volatile("s_waitcnt vmcnt(8)" ::: "memory");
    else                    asm volatile("s_waitcnt vmcnt(6)" ::: "memory");
    __builtin_amdgcn_s_barrier();
    asm volatile("" ::: "memory");

    for (int t = 0; t < NT; ++t) {
        const char* buf = smem + (t & 1) * BUF;
        bf16x8 bfr[4], af[MR];

        #pragma unroll
        for (int kk = 0; kk < 2; ++kk) {
            #pragma unroll
            for (int fc = 0; fc < 4; ++fc)
                bfr[fc] = *(const bf16x8*)(buf + 2 * AH + kk * BH +
                                           frag_off(wn * 64 + fc * 16 + l15));
            #pragma unroll
            for (int i = 0; i < MR; ++i)
                af[i] = *(const bf16x8*)(buf + kk * AH +
                                         frag_off(wm * (BM / 2) + i * 16 + l15));
            if (kk == 0) {
                const int tt = (t + 1 <= NTm1) ? t + 1 : NTm1;
                stageAB(tt, 1, (t + 1) & 1);
            } else {
                const int tt = (t + 2 <= NTm1) ? t + 2 : NTm1;
                stageAB(tt, 0, t & 1);
            }
            if constexpr (GRP == 4) asm volatile("s_waitcnt vmcnt(8)" ::: "memory");
            else                    asm volatile("s_waitcnt vmcnt(6)" ::: "memory");
            __builtin_amdgcn_s_barrier();
            asm volatile("" ::: "memory");
            __builtin_amdgcn_s_setprio(1);
            #pragma unroll
            for (int i = 0; i < MR; ++i)
                #pragma unroll
                for (int fc = 0; fc < 4; ++fc)
                    acc[i][fc] = mfma16(af[i], bfr[fc], acc[i][fc]);
            __builtin_amdgcn_s_setprio(0);
            asm volatile("" ::: "memory");
        }
    }

    float bv[4];
    #pragma unroll
    for (int fc = 0; fc < 4; ++fc) bv[fc] = bias[n0 + wn * 64 + fc * 16 + l15];

    if (EPI == 3 && n0 >= 2048) {
        // V-block: write Vt[(b*16+h)][d][s], b = row>>11, s = row&2047
        #pragma unroll
        for (int fr = 0; fr < MR; ++fr) {
            const int rowg = m0 + wm * (BM / 2) + fr * 16 + l4 * 4;
            const int b = rowg >> 11, srow = rowg & 2047;
            #pragma unroll
            for (int fc = 0; fc < 4; ++fc) {
                const int colv = n0 + wn * 64 + fc * 16 + l15 - 2048;
                const int h = colv >> 6, d = colv & 63;
                u16* vp = VtOut + ((size_t)(b * 16 + h) * 64 + d) * 2048 + srow;
                uint2 w;
                w.x = cvtpk(acc[fr][fc][0] + bv[fc], acc[fr][fc][1] + bv[fc]);
                w.y = cvtpk(acc[fr][fc][2] + bv[fc], acc[fr][fc][3] + bv[fc]);
                *(uint2*)vp = w;
            }
        }
        return;
    }

    #pragma unroll
    for (int fr = 0; fr < MR; ++fr) {
        const int rowg = m0 + wm * (BM / 2) + fr * 16 + l4 * 4;
        #pragma unroll
        for (int fc = 0; fc < 4; ++fc) {
            const int colg = n0 + wn * 64 + fc * 16 + l15;
            #pragma unroll
            for (int r = 0; r < 4; ++r) {
                const float v = acc[fr][fc][r] + bv[fc];
                const size_t off = (size_t)(rowg + r) * N + colg;
                if (EPI == 2) ((u16*)Cout)[off] = f2bf(gelu_f(v));
                else          ((u16*)Cout)[off] = f2bf(v);
            }
        }
    }
}

// ---------- flash attention: QBLK=256, 8 waves; XCD-aligned grid ----------
__global__ __launch_bounds__(512)
void attn_kernel(const u16* __restrict__ QKV, const u16* __restrict__ Vt,
                 u16* __restrict__ ctx)
{
    __shared__ u16 smem[24576];

    const int tid = threadIdx.x;
    const int wid = tid >> 6, lane = tid & 63;
    const int l15 = lane & 15, l4 = lane >> 4;
    const int sw  = l15 & 7;
    const int lr  = lane >> 3;
    const int gsrc = ((lane & 7) ^ lr) * 8;
    const int g   = blockIdx.x;
    const int bh  = (g & 7) | ((g >> 6) << 3);
    const int qt  = (g >> 3) & 7;
    const int b = bh >> 4, h = bh & 15;
    const size_t qrow0 = (size_t)b * 2048 + (size_t)qt * 256;

    u16* const K0 = smem + 16384;
    u16* const V0 = smem + 20480;
    u16* const K1 = smem;
    u16* const V1 = smem + 4096;

    const u16* Qbase = QKV + h * 64;
    const u16* Kbase = QKV + (size_t)b * 2048 * 3072 + 1024 + h * 64;
    const u16* Vbase = Vt + (size_t)bh * 64 * 2048;

    #pragma unroll
    for (int c = 0; c < 4; ++c) {
        const int chunk = wid * 4 + c;
        const int row = chunk * 8 + lr;
        gld_lds16(Qbase + (qrow0 + row) * 3072 + gsrc,
                  (char*)smem + chunk * 1024);
    }

    auto stage_kv = [&](int kt, u16* kb, u16* vb) {
        const int rho = wid * 8 + lr;
        const int krow = (rho & 32) + ((rho & 16) >> 2) + ((rho & 12) << 1) + (rho & 3);
        gld_lds16(Kbase + (size_t)(kt + krow) * 3072 + gsrc,
                  (char*)kb + wid * 1024);
        gld_lds16(Vbase + (size_t)rho * 2048 + kt + gsrc,
                  (char*)vb + wid * 1024);
    };

    stage_kv(0, K0, V0);
    __syncthreads();

    bf16x8 qf[2][2];
    #pragma unroll
    for (int mi = 0; mi < 2; ++mi)
        #pragma unroll
        for (int kk = 0; kk < 2; ++kk)
            qf[mi][kk] = *(const bf16x8*)
                &smem[(size_t)(wid * 32 + mi * 16 + l15) * 64 + (((kk * 4 + l4) ^ sw) * 8)];
    __syncthreads();

    f32x4 accO[2][4] = {};
    f32x4 accL[2] = {};
    const short one_bf = (short)0x3F80;
    const bf16x8 ones = {one_bf, one_bf, one_bf, one_bf,
                         one_bf, one_bf, one_bf, one_bf};
    const f32x4 zf = {0.f, 0.f, 0.f, 0.f};

    union U4 { unsigned u[4]; bf16x8 v; };

    auto compute_tile = [&](const u16* kb, const u16* vb) {
        f32x4 st[2][4];
        __builtin_amdgcn_s_setprio(1);
        #pragma unroll
        for (int ni = 0; ni < 4; ++ni) {
            bf16x8 kf0 = *(const bf16x8*)&kb[(ni * 16 + l15) * 64 + ((l4 ^ sw) * 8)];
            bf16x8 kf1 = *(const bf16x8*)&kb[(ni * 16 + l15) * 64 + (((4 + l4) ^ sw) * 8)];
            #pragma unroll
            for (int mi = 0; mi < 2; ++mi)
                st[mi][ni] = mfma16(kf1, qf[mi][1],
                                    mfma16(kf0, qf[mi][0], zf));
        }
        __builtin_amdgcn_s_setprio(0);

        U4 pb[2][2];
        #pragma unroll
        for (int mi = 0; mi < 2; ++mi) {
            float p[4][4];
            #pragma unroll
            for (int ni = 0; ni < 4; ++ni)
                #pragma unroll
                for (int r = 0; r < 4; ++r)
                    p[ni][r] = fexp2(st[mi][ni][r]);
            #pragma unroll
            for (int ni = 0; ni < 4; ++ni) {
                pb[mi][ni >> 1].u[(ni & 1) * 2 + 0] = cvtpk(p[ni][0], p[ni][1]);
                pb[mi][ni >> 1].u[(ni & 1) * 2 + 1] = cvtpk(p[ni][2], p[ni][3]);
            }
        }

        __builtin_amdgcn_s_setprio(1);
        #pragma unroll
        for (int mi = 0; mi < 2; ++mi) {
            accL[mi] = mfma16(ones, pb[mi][0].v, accL[mi]);
            accL[mi] = mfma16(ones, pb[mi][1].v, accL[mi]);
        }
        #pragma unroll
        for (int di = 0; di < 4; ++di) {
            bf16x8 vf0 = *(const bf16x8*)&vb[(di * 16 + l15) * 64 + ((l4 ^ sw) * 8)];
            bf16x8 vf1 = *(const bf16x8*)&vb[(di * 16 + l15) * 64 + (((4 + l4) ^ sw) * 8)];
            #pragma unroll
            for (int mi = 0; mi < 2; ++mi) {
                accO[mi][di] = mfma16(vf0, pb[mi][0].v, accO[mi][di]);
                accO[mi][di] = mfma16(vf1, pb[mi][1].v, accO[mi][di]);
            }
        }
        __builtin_amdgcn_s_setprio(0);
    };

    for (int it = 0; it < 32; it += 2) {
        if (it + 1 < 32) stage_kv((it + 1) * 64, K1, V1);
        compute_tile(K0, V0);
        __syncthreads();
        if (it + 2 < 32) stage_kv((it + 2) * 64, K0, V0);
        compute_tile(K1, V1);
        __syncthreads();
    }

    #pragma unroll
    for (int mi = 0; mi < 2; ++mi) {
        const float inv = 1.0f / accL[mi][0];
        const size_t q = qrow0 + wid * 32 + mi * 16 + l15;
        #pragma unroll
        for (int di = 0; di < 4; ++di) {
            uint2 w;
            w.x = cvtpk(accO[mi][di][0] * inv, accO[mi][di][1] * inv);
            w.y = cvtpk(accO[mi][di][2] * inv, accO[mi][di][3] * inv);
            *(uint2*)&ctx[q * 1024 + h * 64 + di * 16 + l4 * 4] = w;
        }
    }
}

// ---------- fused add + layernorm; X,Y bf16; outputs f32 and/or bf16 ----------
__global__ __launch_bounds__(256)
void add_ln_kernel(const u16* __restrict__ X, const u16* __restrict__ Y,
                   const float* __restrict__ gamma, const float* __restrict__ beta,
                   float* __restrict__ outf, u16* __restrict__ outb)
{
    const int row = blockIdx.x;
    const int t = threadIdx.x;
    const ushort4 xb = ((const ushort4*)(X + (size_t)row * 1024))[t];
    const ushort4 yb = ((const ushort4*)(Y + (size_t)row * 1024))[t];
    const float v0 = bf2f(xb.x) + bf2f(yb.x);
    const float v1 = bf2f(xb.y) + bf2f(yb.y);
    const float v2 = bf2f(xb.z) + bf2f(yb.z);
    const float v3 = bf2f(xb.w) + bf2f(yb.w);
    float s  = v0 + v1 + v2 + v3;
    float ss = v0 * v0 + v1 * v1 + v2 * v2 + v3 * v3;
    #pragma unroll
    for (int m = 1; m < 64; m <<= 1) {
        s  += __shfl_xor(s, m, 64);
        ss += __shfl_xor(ss, m, 64);
    }
    __shared__ float red[8];
    const int wid = t >> 6, lane = t & 63;
    if (lane == 0) { red[wid] = s; red[4 + wid] = ss; }
    __syncthreads();
    s  = red[0] + red[1] + red[2] + red[3];
    ss = red[4] + red[5] + red[6] + red[7];
    const float mu  = s * (1.f / 1024.f);
    const float var = ss * (1.f / 1024.f) - mu * mu;
    const float inv = rsqrtf(var + 1e-5f);
    const float4 g  = ((const float4*)gamma)[t];
    const float4 bb = ((const float4*)beta)[t];
    float4 o;
    o.x = (v0 - mu) * inv * g.x + bb.x;
    o.y = (v1 - mu) * inv * g.y + bb.y;
    o.z = (v2 - mu) * inv * g.z + bb.z;
    o.w = (v3 - mu) * inv * g.w + bb.w;
    if (outf != nullptr)
        ((float4*)(outf + (size_t)row * 1024))[t] = o;
    if (outb != nullptr) {
        ushort4 ob = make_ushort4(f2bf(o.x), f2bf(o.y), f2bf(o.z), f2bf(o.w));
        ((ushort4*)(outb + (size_t)row * 1024))[t] = ob;
    }
}

// ---------- launcher ----------
extern "C" void kernel_launch(void* const* d_in, const int* in_sizes, int n_in,
                              void* d_out, int out_size, void* d_ws, size_t ws_size,
                              hipStream_t stream)
{
    (void)in_sizes; (void)n_in; (void)out_size; (void)ws_size;
    const float* x   = (const float*)d_in[0];
    const float* Wq  = (const float*)d_in[1];
    const float* bq  = (const float*)d_in[2];
    const float* Wk  = (const float*)d_in[3];
    const float* bk  = (const float*)d_in[4];
    const float* Wv  = (const float*)d_in[5];
    const float* bv  = (const float*)d_in[6];
    const float* Wo  = (const float*)d_in[7];
    const float* bo  = (const float*)d_in[8];
    const float* g1  = (const float*)d_in[9];
    const float* be1 = (const float*)d_in[10];
    const float* W1  = (const float*)d_in[11];
    const float* b1  = (const float*)d_in[12];
    const float* W2  = (const float*)d_in[13];
    const float* b2  = (const float*)d_in[14];
    const float* g2  = (const float*)d_in[15];
    const float* be2 = (const float*)d_in[16];

    constexpr int M = 8192;
    constexpr int D = 1024;
    constexpr int F = 4096;

    char* ws = (char*)d_ws;
    size_t off = 0;
    auto nxt = [&](size_t bytes) -> char* {
        char* p = ws + off;
        off += (bytes + 255) & ~(size_t)255;
        return p;
    };
    u16*   xb    = (u16*)nxt((size_t)M * D * 2);
    u16*   wqkvt = (u16*)nxt((size_t)3 * D * D * 2);
    u16*   wot   = (u16*)nxt((size_t)D * D * 2);
    u16*   w1t   = (u16*)nxt((size_t)F * D * 2);
    u16*   w2t   = (u16*)nxt((size_t)D * F * 2);
    float* bqkv  = (float*)nxt(3072 * 4);
    u16*   qkv   = (u16*)nxt((size_t)M * 3 * D * 2);
    u16*   Vtb   = (u16*)nxt((size_t)M * D * 2);
    u16*   ctx   = (u16*)nxt((size_t)M * D * 2);
    u16*   attn  = (u16*)nxt((size_t)M * D * 2);
    u16*   hb    = (u16*)nxt((size_t)M * D * 2);
    u16*   t1    = qkv;
    u16*   mlp   = attn;

    // 1. merged prepass (weights tcast + x cast + bias concat)
    prepass_kernel<<<dim3(16385), dim3(256), 0, stream>>>(
        Wq, Wk, Wv, Wo, W1, W2, x, bq, bk, bv, wqkvt, wot, w1t, w2t, xb, bqkv);

    constexpr size_t LDS128 = 2 * (2 * 128 * 64 + 2 * 16384);   //  98304
    constexpr size_t LDS256 = 2 * (2 * 256 * 64 + 2 * 16384);   // 131072

    // 2. fused QKV projection; V-blocks write Vt directly (vtrans eliminated)
    gemm_pipe_kernel<128, 3><<<dim3((M / 128) * (3 * D / 256)), dim3(512), LDS128, stream>>>(
        xb, wqkvt, bqkv, qkv, Vtb, M, 3 * D, D);

    // 3. attention (QBLK=256, XCD-aligned 1-D grid)
    attn_kernel<<<dim3(512), dim3(512), 0, stream>>>(qkv, Vtb, ctx);

    // 4. O projection (bf16 out) + LN1 (bf16 residual chain)
    gemm_pipe_kernel<128, 0><<<dim3((M / 128) * (D / 256)), dim3(512), LDS128, stream>>>(
        ctx, wot, bo, attn, nullptr, M, D, D);
    add_ln_kernel<<<dim3(M), dim3(256), 0, stream>>>(xb, attn, g1, be1, nullptr, hb);

    // 5. MLP (256^2 tile for MLP1) + LN2
    gemm_pipe_kernel<256, 2><<<dim3((M / 256) * (F / 256)), dim3(512), LDS256, stream>>>(
        hb, w1t, b1, t1, nullptr, M, F, D);
    gemm_pipe_kernel<128, 0><<<dim3((M / 128) * (D / 256)), dim3(512), LDS128, stream>>>(
        t1, w2t, b2, mlp, nullptr, M, D, F);
    add_ln_kernel<<<dim3(M), dim3(256), 0, stream>>>(hb, mlp, g2, be2, (float*)d_out, nullptr);
}